// Round 6
// baseline (298.000 us; speedup 1.0000x reference)
//
#include <hip/hip_runtime.h>
#include <hip/hip_bf16.h>
#include <math.h>

#define BATCH   16
#define SEQL    512
#define NVARS   32
#define PATCHL  16
#define LTOK    32
#define DMODEL  128
#define NLAYER  2
#define DIN     256
#define DSTATE  16
#define DTRANK  8
#define DCONV   4
#define PRED    96
#define TOK     1024
#define NTOK    (BATCH*TOK)   // 16384
#define EPSF    1e-5f
#define NCH     128           // time chunks
#define CHL     8             // TOK/NCH

typedef __attribute__((ext_vector_type(8))) short bf16x8;
typedef __attribute__((ext_vector_type(4))) float f32x4;
typedef __hip_bfloat16 bf16;

// ---------------------------------------------------------------------------
// K0: cast all GEMM weights to bf16 (concatenated into wbf)
// ---------------------------------------------------------------------------
__global__ __launch_bounds__(256) void k_cast(
    const float* __restrict__ a, const float* __restrict__ b,
    const float* __restrict__ c, const float* __restrict__ d,
    int na, int nb, int nc, int nd, bf16* __restrict__ out)
{
    int i = blockIdx.x * 256 + threadIdx.x;
    int total = na + nb + nc + nd;
    if (i >= total) return;
    float v;
    if (i < na) v = a[i];
    else if (i < na + nb) v = b[i - na];
    else if (i < na + nb + nc) v = c[i - na - nb];
    else v = d[i - na - nb - nc];
    out[i] = __float2bfloat16(v);
}

// ---------------------------------------------------------------------------
// K0b: per-(layer,d) scan constants: a1 = -exp(A_log[...,0]) and the
// "power-law" flag (A_n == (n+1)*A_0), checked once instead of per-thread.
// ---------------------------------------------------------------------------
__global__ __launch_bounds__(256) void k_prep(
    const float* __restrict__ A_log, float* __restrict__ a1s, int* __restrict__ pwf)
{
    int i = blockIdx.x * 256 + threadIdx.x;   // NLAYER*DIN = 512
    if (i >= NLAYER * DIN) return;
    const float* al = A_log + (size_t)i * DSTATE;
    float a1 = -__expf(al[0]);
    bool pw = true;
    #pragma unroll
    for (int n = 1; n < 16; n++) {
        float av = -__expf(al[n]);
        pw = pw && (fabsf(av - (n + 1) * a1) <= 1e-5f * fabsf((n + 1) * a1));
    }
    a1s[i] = a1;
    pwf[i] = pw ? 1 : 0;
}

// ---------------------------------------------------------------------------
// K1: per-(b,c) instance norm over time + patch embedding
// ---------------------------------------------------------------------------
__global__ __launch_bounds__(256) void k_instnorm_patch(
    const float* __restrict__ x_enc, const float* __restrict__ patch_w,
    float* __restrict__ x, float* __restrict__ means, float* __restrict__ stdev)
{
    int bc = blockIdx.x;
    int b = bc >> 5, c = bc & 31;
    __shared__ float xe[SEQL];
    __shared__ float pw[DMODEL * PATCHL];
    __shared__ float red[8];
    int tid = threadIdx.x;

    float v0 = x_enc[((size_t)b * SEQL + tid) * NVARS + c];
    float v1 = x_enc[((size_t)b * SEQL + tid + 256) * NVARS + c];
    for (int i = tid; i < DMODEL * PATCHL; i += 256) pw[i] = patch_w[i];

    float s = v0 + v1;
    for (int o = 1; o < 64; o <<= 1) s += __shfl_xor(s, o, 64);
    if ((tid & 63) == 0) red[tid >> 6] = s;
    __syncthreads();
    float mean = (red[0] + red[1] + red[2] + red[3]) * (1.f / 512.f);

    float d0 = v0 - mean, d1 = v1 - mean;
    float q = d0 * d0 + d1 * d1;
    for (int o = 1; o < 64; o <<= 1) q += __shfl_xor(q, o, 64);
    if ((tid & 63) == 0) red[4 + (tid >> 6)] = q;
    __syncthreads();
    float var = (red[4] + red[5] + red[6] + red[7]) * (1.f / 512.f);
    float sd = sqrtf(var + EPSF);
    float rsd = 1.f / sd;
    if (tid == 0) { means[bc] = mean; stdev[bc] = sd; }

    xe[tid] = d0 * rsd;
    xe[tid + 256] = d1 * rsd;
    __syncthreads();

    size_t base = ((size_t)b * TOK + (size_t)c * LTOK) * DMODEL;
    for (int o = tid; o < LTOK * DMODEL; o += 256) {
        int l = o >> 7, dm = o & 127;
        float acc = 0.f;
        #pragma unroll
        for (int p = 0; p < PATCHL; p++) acc += xe[l * PATCHL + p] * pw[dm * PATCHL + p];
        x[base + o] = acc;
    }
}

// ---------------------------------------------------------------------------
// K2: RMSNorm over last dim (128), bf16 output. One wave per token.
// ---------------------------------------------------------------------------
__global__ __launch_bounds__(256) void k_rmsnorm(
    const float* __restrict__ in, const float* __restrict__ w,
    bf16* __restrict__ out)
{
    int wave = threadIdx.x >> 6, lane = threadIdx.x & 63;
    int tok = blockIdx.x * 4 + wave;
    const float* r = in + (size_t)tok * DMODEL;
    float a = r[lane], bv = r[lane + 64];
    float q = a * a + bv * bv;
    for (int o = 1; o < 64; o <<= 1) q += __shfl_xor(q, o, 64);
    float rms = rsqrtf(q * (1.f / DMODEL) + EPSF);
    bf16* o_ = out + (size_t)tok * DMODEL;
    o_[lane]      = __float2bfloat16(a  * rms * w[lane]);
    o_[lane + 64] = __float2bfloat16(bv * rms * w[lane + 64]);
}

// ---------------------------------------------------------------------------
// K3: MFMA bf16 GEMM.  C op= A[M,K](lda) @ W[N,K]^T  (f32 accum)
// 128x128 tile, BK=32, 4 waves (2x2), 16 MFMA(16x16x32)/wave/K-step.
// MODE: 0=store f32 C, 2=atomicAdd f32 C, 3=split bf16 (n<256 -> C3, else C2).
// ---------------------------------------------------------------------------
template <int MODE>
__global__ __launch_bounds__(256) void mfma_gemm(
    const bf16* __restrict__ A, const bf16* __restrict__ W,
    float* __restrict__ C, bf16* __restrict__ C2, bf16* __restrict__ C3,
    int M, int N, int K, int lda, int kper)
{
    __shared__ ushort Asm[128][40];   // 80B row stride: frag reads 2-way only
    __shared__ ushort Wsm[128][40];
    int bm = blockIdx.y * 128, bn = blockIdx.x * 128;
    int tid = threadIdx.x;
    int w = tid >> 6, l = tid & 63;
    int wr = w >> 1, wc = w & 1;
    int kb = (l >> 4) * 8, lr = l & 15;

    f32x4 acc[4][4];
    #pragma unroll
    for (int i = 0; i < 4; i++)
        #pragma unroll
        for (int j = 0; j < 4; j++) acc[i][j] = (f32x4){0.f, 0.f, 0.f, 0.f};

    int kbeg = blockIdx.z * kper;
    for (int k0 = kbeg; k0 < kbeg + kper; k0 += 32) {
        #pragma unroll
        for (int i = 0; i < 2; i++) {
            int idx = tid + 256 * i;
            int row = idx >> 2, kq = (idx & 3) * 8;
            *(float4*)&Asm[row][kq] =
                *(const float4*)&A[(size_t)(bm + row) * lda + k0 + kq];
            float4 wv = make_float4(0.f, 0.f, 0.f, 0.f);
            if (bn + row < N)
                wv = *(const float4*)&W[(size_t)(bn + row) * K + k0 + kq];
            *(float4*)&Wsm[row][kq] = wv;
        }
        __syncthreads();
        bf16x8 af[4], bfr[4];
        #pragma unroll
        for (int f = 0; f < 4; f++) {
            af[f]  = *(const bf16x8*)&Asm[wr * 64 + f * 16 + lr][kb];
            bfr[f] = *(const bf16x8*)&Wsm[wc * 64 + f * 16 + lr][kb];
        }
        #pragma unroll
        for (int mf = 0; mf < 4; mf++)
            #pragma unroll
            for (int nf = 0; nf < 4; nf++)
                acc[mf][nf] = __builtin_amdgcn_mfma_f32_16x16x32_bf16(
                    af[mf], bfr[nf], acc[mf][nf], 0, 0, 0);
        __syncthreads();
    }

    // C/D layout: col = lane&15, row = (lane>>4)*4 + reg
    int rbase = bm + wr * 64 + (l >> 4) * 4;
    int cbase = bn + wc * 64 + lr;
    #pragma unroll
    for (int mf = 0; mf < 4; mf++) {
        #pragma unroll
        for (int nf = 0; nf < 4; nf++) {
            int n = cbase + nf * 16;
            if (n >= N) continue;
            #pragma unroll
            for (int r = 0; r < 4; r++) {
                int m = rbase + mf * 16 + r;
                float v = acc[mf][nf][r];
                if (MODE == 0) C[(size_t)m * N + n] = v;
                else if (MODE == 2) atomicAdd(&C[(size_t)m * N + n], v);
                else {  // MODE 3: in_proj split store (N==512), both bf16
                    if (n < 256) C3[(size_t)m * 256 + n] = __float2bfloat16(v);
                    else C2[(size_t)m * 256 + (n - 256)] = __float2bfloat16(v);
                }
            }
        }
    }
}

// ---------------------------------------------------------------------------
// K4: causal depthwise conv (k=4) + bias + SiLU ; xs bf16 -> u bf16
// ---------------------------------------------------------------------------
__global__ __launch_bounds__(256) void k_conv(
    const bf16* __restrict__ xs, const float* __restrict__ cw,
    const float* __restrict__ cb, bf16* __restrict__ ubf)
{
    int idx = blockIdx.x * 256 + threadIdx.x;
    int d = idx & 255;
    int t = (idx >> 8) & 1023;
    int b = idx >> 18;
    const bf16* col = xs + (size_t)b * TOK * 256 + d;
    float acc = cb[d];
    #pragma unroll
    for (int j = 0; j < DCONV; j++) {
        int tt = t - (DCONV - 1) + j;
        if (tt >= 0) acc += __bfloat162float(col[(size_t)tt * 256]) * cw[d * DCONV + j];
    }
    float s = __fdividef(acc, 1.f + __expf(-acc));
    ubf[idx] = __float2bfloat16(s);
}

// ---------------------------------------------------------------------------
// Scan, chunked 3-phase (NCH=128, CHL=8). Thread owns one d, 16 n-states.
// xdbl rows read via block-uniform global loads (-> s_load).
// scan1 computes dt (softplus of dt-proj) and STORES it for scan3.
// ---------------------------------------------------------------------------
__device__ __forceinline__ float softplus_f(float x) {
    return (x > 8.f) ? x : __logf(1.f + __expf(x));
}

__global__ __launch_bounds__(256) void k_scan1(
    const bf16* __restrict__ ubf, const float* __restrict__ xdbl,
    const float* __restrict__ dtw, const float* __restrict__ dtb_,
    const float* __restrict__ a1s, const int* __restrict__ pwf,
    const float* __restrict__ A_log,
    float* __restrict__ q, float* __restrict__ sdt_out,
    float* __restrict__ dtv_out)
{
    int blk = blockIdx.x;                 // b*NCH + ch
    int b = blk >> 7, ch = blk & (NCH - 1);
    int d = threadIdx.x;

    float a1 = a1s[d];
    bool pw = pwf[d] != 0;
    float w8[8];
    #pragma unroll
    for (int j = 0; j < 8; j++) w8[j] = dtw[d * 8 + j];
    float bias = dtb_[d];
    float h[16];
    #pragma unroll
    for (int n = 0; n < 16; n++) h[n] = 0.f;
    float sdt = 0.f;

    size_t tok0 = (size_t)b * TOK + ch * CHL;
    const float* row = xdbl + tok0 * 40;
    const bf16* up = ubf + tok0 * 256 + d;
    float* dvp = dtv_out + tok0 * 256 + d;

    if (pw) {
        for (int t = 0; t < CHL; t++, row += 40, up += 256, dvp += 256) {
            float acc = bias;
            #pragma unroll
            for (int j = 0; j < 8; j++) acc += row[j] * w8[j];
            float dtv = softplus_f(acc);
            *dvp = dtv;
            float uu = __bfloat162float(*up);
            sdt += dtv;
            float du = dtv * uu;
            float dA[16];
            dA[0] = __expf(dtv * a1);
            #pragma unroll
            for (int n = 1; n < 16; n++) dA[n] = dA[(n - 1) >> 1] * dA[n >> 1];
            #pragma unroll
            for (int n = 0; n < 16; n++)
                h[n] = dA[n] * h[n] + du * row[8 + n];
        }
    } else {
        float Av[16];
        #pragma unroll
        for (int n = 0; n < 16; n++) Av[n] = -__expf(A_log[d * 16 + n]);
        for (int t = 0; t < CHL; t++, row += 40, up += 256, dvp += 256) {
            float acc = bias;
            #pragma unroll
            for (int j = 0; j < 8; j++) acc += row[j] * w8[j];
            float dtv = softplus_f(acc);
            *dvp = dtv;
            float uu = __bfloat162float(*up);
            sdt += dtv;
            float du = dtv * uu;
            #pragma unroll
            for (int n = 0; n < 16; n++)
                h[n] = __expf(dtv * Av[n]) * h[n] + du * row[8 + n];
        }
    }
    float* qp = q + ((size_t)blk * 256 + d) * 16;
    #pragma unroll
    for (int n = 0; n < 16; n += 4)
        *(float4*)(qp + n) = make_float4(h[n], h[n+1], h[n+2], h[n+3]);
    sdt_out[(size_t)blk * 256 + d] = sdt;
}

__global__ __launch_bounds__(256) void k_scan2(
    const float* __restrict__ A_log, const float* __restrict__ sdt_in,
    float* __restrict__ q)
{
    int idx = blockIdx.x * 256 + threadIdx.x;   // (b,d,n): 65536
    int n = idx & 15, d = (idx >> 4) & 255, b = idx >> 12;
    float Av = -__expf(A_log[d * 16 + n]);
    float h = 0.f;
    for (int ch = 0; ch < NCH; ch++) {
        size_t base = ((size_t)(b * NCH + ch) * 256 + d);
        float qv = q[base * 16 + n];
        float P = __expf(Av * sdt_in[base]);
        q[base * 16 + n] = h;
        h = P * h + qv;
    }
}

__global__ __launch_bounds__(256) void k_scan3(
    const bf16* __restrict__ ubf, const float* __restrict__ dtv_in,
    const float* __restrict__ xdbl,
    const float* __restrict__ a1s, const int* __restrict__ pwf,
    const float* __restrict__ A_log, const float* __restrict__ Dp,
    const float* __restrict__ q, const bf16* __restrict__ zbf,
    bf16* __restrict__ ybf)
{
    int blk = blockIdx.x;
    int b = blk >> 7, ch = blk & (NCH - 1);
    int d = threadIdx.x;

    float a1 = a1s[d];
    bool pw = pwf[d] != 0;
    float Dv = Dp[d];
    float h[16];
    const float* qp = q + ((size_t)blk * 256 + d) * 16;
    #pragma unroll
    for (int n = 0; n < 16; n += 4) {
        float4 v = *(const float4*)(qp + n);
        h[n] = v.x; h[n+1] = v.y; h[n+2] = v.z; h[n+3] = v.w;
    }

    size_t tok0 = (size_t)b * TOK + ch * CHL;
    const float* row = xdbl + tok0 * 40;
    const bf16* up = ubf + tok0 * 256 + d;
    const float* dvp = dtv_in + tok0 * 256 + d;
    const bf16* zp = zbf + tok0 * 256 + d;
    bf16* yp = ybf + tok0 * 256 + d;

    if (pw) {
        for (int t = 0; t < CHL; t++, row += 40, up += 256, dvp += 256, zp += 256, yp += 256) {
            float dtv = *dvp;
            float uu = __bfloat162float(*up);
            float du = dtv * uu;
            float dA[16];
            dA[0] = __expf(dtv * a1);
            #pragma unroll
            for (int n = 1; n < 16; n++) dA[n] = dA[(n - 1) >> 1] * dA[n >> 1];
            float ya = 0.f;
            #pragma unroll
            for (int n = 0; n < 16; n++) {
                h[n] = dA[n] * h[n] + du * row[8 + n];
                ya += h[n] * row[24 + n];
            }
            float zv = __bfloat162float(*zp);
            float sz = __fdividef(zv, 1.f + __expf(-zv));
            *yp = __float2bfloat16((ya + uu * Dv) * sz);
        }
    } else {
        float Av[16];
        #pragma unroll
        for (int n = 0; n < 16; n++) Av[n] = -__expf(A_log[d * 16 + n]);
        for (int t = 0; t < CHL; t++, row += 40, up += 256, dvp += 256, zp += 256, yp += 256) {
            float dtv = *dvp;
            float uu = __bfloat162float(*up);
            float du = dtv * uu;
            float ya = 0.f;
            #pragma unroll
            for (int n = 0; n < 16; n++) {
                h[n] = __expf(dtv * Av[n]) * h[n] + du * row[8 + n];
                ya += h[n] * row[24 + n];
            }
            float zv = __bfloat162float(*zp);
            float sz = __fdividef(zv, 1.f + __expf(-zv));
            *yp = __float2bfloat16((ya + uu * Dv) * sz);
        }
    }
}

// ---------------------------------------------------------------------------
// K7: head epilogue: out[b,p,c] = (hg[(b*32+c)*96+p] + hb[p]) * stdev + mean
// ---------------------------------------------------------------------------
__global__ __launch_bounds__(256) void k_head_ep(
    const float* __restrict__ hg, const float* __restrict__ hb,
    const float* __restrict__ means, const float* __restrict__ stdev,
    float* __restrict__ out)
{
    int i = blockIdx.x * 256 + threadIdx.x;
    if (i >= BATCH * PRED * NVARS) return;
    int c = i & 31;
    int p = (i >> 5) % PRED;
    int b = i / (PRED * NVARS);
    float v = hg[((size_t)b * NVARS + c) * PRED + p] + hb[p];
    out[i] = v * stdev[b * NVARS + c] + means[b * NVARS + c];
}

// ---------------------------------------------------------------------------
extern "C" void kernel_launch(void* const* d_in, const int* in_sizes, int n_in,
                              void* d_out, int out_size, void* d_ws, size_t ws_size,
                              hipStream_t stream)
{
    const float* x_enc   = (const float*)d_in[0];
    const float* patch_w = (const float*)d_in[4];
    const float* norm_w  = (const float*)d_in[5];
    const float* in_w    = (const float*)d_in[6];
    const float* conv_w  = (const float*)d_in[7];
    const float* conv_b  = (const float*)d_in[8];
    const float* xp_w    = (const float*)d_in[9];
    const float* dt_w    = (const float*)d_in[10];
    const float* dt_b    = (const float*)d_in[11];
    const float* A_log   = (const float*)d_in[12];
    const float* D_skip  = (const float*)d_in[13];
    const float* out_w   = (const float*)d_in[14];
    const float* fnorm_w = (const float*)d_in[15];
    const float* head_w  = (const float*)d_in[16];
    const float* head_b  = (const float*)d_in[17];
    float* out = (float*)d_out;

    float* ws    = (float*)d_ws;
    float* means = ws;                          // 512
    float* stdv  = ws + 512;                    // 512
    float* x     = ws + 1024;                   // NTOK*128 f32   8MB
    float* xdbl  = x    + (size_t)NTOK * 128;   // NTOK*40      2.6MB
    float* dtb   = xdbl + (size_t)NTOK * 40;    // NTOK*256      16MB
    float* qbuf  = dtb  + (size_t)NTOK * 256;   // 16*128*256*16 33.5MB
    float* sbuf  = qbuf + (size_t)BATCH * NCH * DIN * DSTATE;  // 2MB
    float* hg    = sbuf + (size_t)BATCH * NCH * DIN;           // 512*96
    float* a1s   = hg + 512 * PRED;             // NLAYER*DIN
    int*   pwf   = (int*)(a1s + NLAYER * DIN);  // NLAYER*DIN
    bf16* hbf  = (bf16*)(pwf + NLAYER * DIN);   // NTOK*128   4MB
    bf16* xsbf = hbf + (size_t)NTOK * 128;      // NTOK*256   8MB
    bf16* zbf  = xsbf + (size_t)NTOK * 256;     // NTOK*256   8MB
    bf16* ubf  = zbf + (size_t)NTOK * 256;      // NTOK*256   8MB
    bf16* ybf  = ubf + (size_t)NTOK * 256;      // NTOK*256   8MB
    bf16* wbf  = ybf + (size_t)NTOK * 256;      // 610304     1.2MB

    const int NIW = NLAYER * 2 * DIN * DMODEL;         // 131072
    const int NXW = NLAYER * (DTRANK + 2*DSTATE) * DIN;// 20480
    const int NOW = NLAYER * DMODEL * DIN;             // 65536
    const int NHW = PRED * LTOK * DMODEL;              // 393216
    bf16* iwbf = wbf;
    bf16* xwbf = iwbf + NIW;
    bf16* owbf = xwbf + NXW;
    bf16* hwbf = owbf + NOW;

    k_cast<<<(NIW + NXW + NOW + NHW + 255) / 256, 256, 0, stream>>>(
        in_w, xp_w, out_w, head_w, NIW, NXW, NOW, NHW, wbf);
    k_prep<<<2, 256, 0, stream>>>(A_log, a1s, pwf);

    k_instnorm_patch<<<BATCH * NVARS, 256, 0, stream>>>(x_enc, patch_w, x, means, stdv);

    for (int layer = 0; layer < NLAYER; layer++) {
        const float* nw  = norm_w + layer * DMODEL;
        const float* cw  = conv_w + layer * DIN * DCONV;
        const float* cb  = conv_b + layer * DIN;
        const float* dw  = dt_w   + layer * DIN * DTRANK;
        const float* db  = dt_b   + layer * DIN;
        const float* al  = A_log  + layer * DIN * DSTATE;
        const float* dp  = D_skip + layer * DIN;
        const float* a1l = a1s + layer * DIN;
        const int*   pwl = pwf + layer * DIN;
        const bf16* iw = iwbf + (size_t)layer * 2 * DIN * DMODEL;
        const bf16* xw = xwbf + (size_t)layer * (DTRANK + 2 * DSTATE) * DIN;
        const bf16* ow = owbf + (size_t)layer * DMODEL * DIN;

        k_rmsnorm<<<NTOK / 4, 256, 0, stream>>>(x, nw, hbf);
        // xz = h @ in_w^T, split: cols 0..255 -> xsbf, 256..511 -> zbf (bf16)
        mfma_gemm<3><<<dim3(4, NTOK / 128, 1), 256, 0, stream>>>(
            hbf, iw, nullptr, zbf, xsbf, NTOK, 512, DMODEL, DMODEL, DMODEL);
        k_conv<<<(NTOK * DIN) / 256, 256, 0, stream>>>(xsbf, cw, cb, ubf);
        // xdbl = u @ xp_w^T
        mfma_gemm<0><<<dim3(1, NTOK / 128, 1), 256, 0, stream>>>(
            ubf, xw, xdbl, nullptr, nullptr, NTOK, DTRANK + 2 * DSTATE, DIN, DIN, DIN);
        k_scan1<<<BATCH * NCH, 256, 0, stream>>>(ubf, xdbl, dw, db, a1l, pwl, al, qbuf, sbuf, dtb);
        k_scan2<<<(BATCH * DIN * DSTATE) / 256, 256, 0, stream>>>(al, sbuf, qbuf);
        k_scan3<<<BATCH * NCH, 256, 0, stream>>>(ubf, dtb, xdbl, a1l, pwl, al, dp, qbuf, zbf, ybf);
        // x += y @ out_w^T  (split-K=4, atomicAdd into residual)
        mfma_gemm<2><<<dim3(1, NTOK / 128, 4), 256, 0, stream>>>(
            ybf, ow, x, nullptr, nullptr, NTOK, DMODEL, DIN, DIN, DIN / 4);
    }

    // final norm -> hbf; head = split-K MFMA into zeroed hg, then epilogue
    k_rmsnorm<<<NTOK / 4, 256, 0, stream>>>(x, fnorm_w, hbf);
    hipMemsetAsync(hg, 0, 512 * PRED * sizeof(float), stream);
    mfma_gemm<2><<<dim3(1, 4, 64), 256, 0, stream>>>(
        hbf, hwbf, hg, nullptr, nullptr, 512, PRED, LTOK * DMODEL, LTOK * DMODEL, 64);
    k_head_ep<<<(BATCH * PRED * NVARS + 255) / 256, 256, 0, stream>>>(
        hg, head_b, means, stdv, out);
}

// Round 7
// 270.492 us; speedup vs baseline: 1.1017x; 1.1017x over previous
//
#include <hip/hip_runtime.h>
#include <hip/hip_bf16.h>
#include <math.h>

#define BATCH   16
#define SEQL    512
#define NVARS   32
#define PATCHL  16
#define LTOK    32
#define DMODEL  128
#define NLAYER  2
#define DIN     256
#define DSTATE  16
#define DTRANK  8
#define DCONV   4
#define PRED    96
#define TOK     1024
#define NTOK    (BATCH*TOK)   // 16384
#define EPSF    1e-5f
#define NCH     64            // time chunks
#define CHL     16            // TOK/NCH

typedef __attribute__((ext_vector_type(8))) short bf16x8;
typedef __attribute__((ext_vector_type(4))) float f32x4;
typedef __hip_bfloat16 bf16;

// ---------------------------------------------------------------------------
// K0: cast all GEMM weights to bf16 (concatenated into wbf)
// ---------------------------------------------------------------------------
__global__ __launch_bounds__(256) void k_cast(
    const float* __restrict__ a, const float* __restrict__ b,
    const float* __restrict__ c, const float* __restrict__ d,
    int na, int nb, int nc, int nd, bf16* __restrict__ out)
{
    int i = blockIdx.x * 256 + threadIdx.x;
    int total = na + nb + nc + nd;
    if (i >= total) return;
    float v;
    if (i < na) v = a[i];
    else if (i < na + nb) v = b[i - na];
    else if (i < na + nb + nc) v = c[i - na - nb];
    else v = d[i - na - nb - nc];
    out[i] = __float2bfloat16(v);
}

// ---------------------------------------------------------------------------
// K0b: per-(layer,d) scan constants: a1 = -exp(A_log[...,0]) and the
// "power-law" flag (A_n == (n+1)*A_0), checked once.
// ---------------------------------------------------------------------------
__global__ __launch_bounds__(256) void k_prep(
    const float* __restrict__ A_log, float* __restrict__ a1s, int* __restrict__ pwf)
{
    int i = blockIdx.x * 256 + threadIdx.x;   // NLAYER*DIN = 512
    if (i >= NLAYER * DIN) return;
    const float* al = A_log + (size_t)i * DSTATE;
    float a1 = -__expf(al[0]);
    bool pw = true;
    #pragma unroll
    for (int n = 1; n < 16; n++) {
        float av = -__expf(al[n]);
        pw = pw && (fabsf(av - (n + 1) * a1) <= 1e-5f * fabsf((n + 1) * a1));
    }
    a1s[i] = a1;
    pwf[i] = pw ? 1 : 0;
}

// ---------------------------------------------------------------------------
// K1: per-(b,c) instance norm over time + patch embedding
// ---------------------------------------------------------------------------
__global__ __launch_bounds__(256) void k_instnorm_patch(
    const float* __restrict__ x_enc, const float* __restrict__ patch_w,
    float* __restrict__ x, float* __restrict__ means, float* __restrict__ stdev)
{
    int bc = blockIdx.x;
    int b = bc >> 5, c = bc & 31;
    __shared__ float xe[SEQL];
    __shared__ float pw[DMODEL * PATCHL];
    __shared__ float red[8];
    int tid = threadIdx.x;

    float v0 = x_enc[((size_t)b * SEQL + tid) * NVARS + c];
    float v1 = x_enc[((size_t)b * SEQL + tid + 256) * NVARS + c];
    for (int i = tid; i < DMODEL * PATCHL; i += 256) pw[i] = patch_w[i];

    float s = v0 + v1;
    for (int o = 1; o < 64; o <<= 1) s += __shfl_xor(s, o, 64);
    if ((tid & 63) == 0) red[tid >> 6] = s;
    __syncthreads();
    float mean = (red[0] + red[1] + red[2] + red[3]) * (1.f / 512.f);

    float d0 = v0 - mean, d1 = v1 - mean;
    float q = d0 * d0 + d1 * d1;
    for (int o = 1; o < 64; o <<= 1) q += __shfl_xor(q, o, 64);
    if ((tid & 63) == 0) red[4 + (tid >> 6)] = q;
    __syncthreads();
    float var = (red[4] + red[5] + red[6] + red[7]) * (1.f / 512.f);
    float sd = sqrtf(var + EPSF);
    float rsd = 1.f / sd;
    if (tid == 0) { means[bc] = mean; stdev[bc] = sd; }

    xe[tid] = d0 * rsd;
    xe[tid + 256] = d1 * rsd;
    __syncthreads();

    size_t base = ((size_t)b * TOK + (size_t)c * LTOK) * DMODEL;
    for (int o = tid; o < LTOK * DMODEL; o += 256) {
        int l = o >> 7, dm = o & 127;
        float acc = 0.f;
        #pragma unroll
        for (int p = 0; p < PATCHL; p++) acc += xe[l * PATCHL + p] * pw[dm * PATCHL + p];
        x[base + o] = acc;
    }
}

// ---------------------------------------------------------------------------
// K2: RMSNorm over last dim (128), bf16 output. One wave per token.
// ---------------------------------------------------------------------------
__global__ __launch_bounds__(256) void k_rmsnorm(
    const float* __restrict__ in, const float* __restrict__ w,
    bf16* __restrict__ out)
{
    int wave = threadIdx.x >> 6, lane = threadIdx.x & 63;
    int tok = blockIdx.x * 4 + wave;
    const float* r = in + (size_t)tok * DMODEL;
    float a = r[lane], bv = r[lane + 64];
    float q = a * a + bv * bv;
    for (int o = 1; o < 64; o <<= 1) q += __shfl_xor(q, o, 64);
    float rms = rsqrtf(q * (1.f / DMODEL) + EPSF);
    bf16* o_ = out + (size_t)tok * DMODEL;
    o_[lane]      = __float2bfloat16(a  * rms * w[lane]);
    o_[lane + 64] = __float2bfloat16(bv * rms * w[lane + 64]);
}

// ---------------------------------------------------------------------------
// K3: MFMA bf16 GEMM.  C op= A[M,K](lda) @ W[N,K]^T  (f32 accum)
// 128x128 tile, BK=32, 4 waves (2x2), 16 MFMA(16x16x32)/wave/K-step.
// MODE: 0=store f32 C, 2=atomicAdd f32 C, 3=split bf16 (n<256 -> C3, else C2).
// ---------------------------------------------------------------------------
template <int MODE>
__global__ __launch_bounds__(256) void mfma_gemm(
    const bf16* __restrict__ A, const bf16* __restrict__ W,
    float* __restrict__ C, bf16* __restrict__ C2, bf16* __restrict__ C3,
    int M, int N, int K, int lda, int kper)
{
    __shared__ ushort Asm[128][40];   // 80B row stride: frag reads 2-way only
    __shared__ ushort Wsm[128][40];
    int bm = blockIdx.y * 128, bn = blockIdx.x * 128;
    int tid = threadIdx.x;
    int w = tid >> 6, l = tid & 63;
    int wr = w >> 1, wc = w & 1;
    int kb = (l >> 4) * 8, lr = l & 15;

    f32x4 acc[4][4];
    #pragma unroll
    for (int i = 0; i < 4; i++)
        #pragma unroll
        for (int j = 0; j < 4; j++) acc[i][j] = (f32x4){0.f, 0.f, 0.f, 0.f};

    int kbeg = blockIdx.z * kper;
    for (int k0 = kbeg; k0 < kbeg + kper; k0 += 32) {
        #pragma unroll
        for (int i = 0; i < 2; i++) {
            int idx = tid + 256 * i;
            int row = idx >> 2, kq = (idx & 3) * 8;
            *(float4*)&Asm[row][kq] =
                *(const float4*)&A[(size_t)(bm + row) * lda + k0 + kq];
            float4 wv = make_float4(0.f, 0.f, 0.f, 0.f);
            if (bn + row < N)
                wv = *(const float4*)&W[(size_t)(bn + row) * K + k0 + kq];
            *(float4*)&Wsm[row][kq] = wv;
        }
        __syncthreads();
        bf16x8 af[4], bfr[4];
        #pragma unroll
        for (int f = 0; f < 4; f++) {
            af[f]  = *(const bf16x8*)&Asm[wr * 64 + f * 16 + lr][kb];
            bfr[f] = *(const bf16x8*)&Wsm[wc * 64 + f * 16 + lr][kb];
        }
        #pragma unroll
        for (int mf = 0; mf < 4; mf++)
            #pragma unroll
            for (int nf = 0; nf < 4; nf++)
                acc[mf][nf] = __builtin_amdgcn_mfma_f32_16x16x32_bf16(
                    af[mf], bfr[nf], acc[mf][nf], 0, 0, 0);
        __syncthreads();
    }

    // C/D layout: col = lane&15, row = (lane>>4)*4 + reg
    int rbase = bm + wr * 64 + (l >> 4) * 4;
    int cbase = bn + wc * 64 + lr;
    #pragma unroll
    for (int mf = 0; mf < 4; mf++) {
        #pragma unroll
        for (int nf = 0; nf < 4; nf++) {
            int n = cbase + nf * 16;
            if (n >= N) continue;
            #pragma unroll
            for (int r = 0; r < 4; r++) {
                int m = rbase + mf * 16 + r;
                float v = acc[mf][nf][r];
                if (MODE == 0) C[(size_t)m * N + n] = v;
                else if (MODE == 2) atomicAdd(&C[(size_t)m * N + n], v);
                else {  // MODE 3: in_proj split store (N==512), both bf16
                    if (n < 256) C3[(size_t)m * 256 + n] = __float2bfloat16(v);
                    else C2[(size_t)m * 256 + (n - 256)] = __float2bfloat16(v);
                }
            }
        }
    }
}

// ---------------------------------------------------------------------------
// K4: causal depthwise conv (k=4) + bias + SiLU ; xs bf16 -> u bf16
// ---------------------------------------------------------------------------
__global__ __launch_bounds__(256) void k_conv(
    const bf16* __restrict__ xs, const float* __restrict__ cw,
    const float* __restrict__ cb, bf16* __restrict__ ubf)
{
    int idx = blockIdx.x * 256 + threadIdx.x;
    int d = idx & 255;
    int t = (idx >> 8) & 1023;
    int b = idx >> 18;
    const bf16* col = xs + (size_t)b * TOK * 256 + d;
    float acc = cb[d];
    #pragma unroll
    for (int j = 0; j < DCONV; j++) {
        int tt = t - (DCONV - 1) + j;
        if (tt >= 0) acc += __bfloat162float(col[(size_t)tt * 256]) * cw[d * DCONV + j];
    }
    float s = __fdividef(acc, 1.f + __expf(-acc));
    ubf[idx] = __float2bfloat16(s);
}

// ---------------------------------------------------------------------------
// Scan, chunked 3-phase (NCH=64, CHL=16). Thread owns one d, 16 n-states,
// and TWO chunks (two independent chains interleaved -> 2x ILP on the
// exp/h-update dependency chain). xdbl rows read as block-uniform loads.
// ---------------------------------------------------------------------------
__device__ __forceinline__ float softplus_f(float x) {
    return (x > 8.f) ? x : __logf(1.f + __expf(x));
}

__global__ __launch_bounds__(256) void k_scan1(
    const bf16* __restrict__ ubf, const float* __restrict__ xdbl,
    const float* __restrict__ dtw, const float* __restrict__ dtb_,
    const float* __restrict__ a1s, const int* __restrict__ pwf,
    const float* __restrict__ A_log,
    float* __restrict__ q, float* __restrict__ sdt_out)
{
    int blk = blockIdx.x;                 // b*(NCH/2) + cp
    int b = blk >> 5, cp = blk & 31;
    int ch0 = cp * 2;
    int d = threadIdx.x;

    float a1 = a1s[d];
    bool pw = pwf[d] != 0;
    float w8[8];
    #pragma unroll
    for (int j = 0; j < 8; j++) w8[j] = dtw[d * 8 + j];
    float bias = dtb_[d];
    float h0[16], h1[16];
    #pragma unroll
    for (int n = 0; n < 16; n++) { h0[n] = 0.f; h1[n] = 0.f; }
    float sdt0 = 0.f, sdt1 = 0.f;

    size_t tokA = (size_t)b * TOK + ch0 * CHL;
    const float* rowA = xdbl + tokA * 40;
    const float* rowB = rowA + CHL * 40;
    const bf16* upA = ubf + tokA * 256 + d;
    const bf16* upB = upA + CHL * 256;

    if (pw) {
        for (int t = 0; t < CHL; t++, rowA += 40, rowB += 40, upA += 256, upB += 256) {
            float accA = bias, accB = bias;
            #pragma unroll
            for (int j = 0; j < 8; j++) { accA += rowA[j] * w8[j]; accB += rowB[j] * w8[j]; }
            float dtA = softplus_f(accA), dtB = softplus_f(accB);
            float uA = __bfloat162float(*upA), uB = __bfloat162float(*upB);
            sdt0 += dtA; sdt1 += dtB;
            float duA = dtA * uA, duB = dtB * uB;
            float dA0[16], dA1[16];
            dA0[0] = __expf(dtA * a1);
            dA1[0] = __expf(dtB * a1);
            #pragma unroll
            for (int n = 1; n < 16; n++) {
                dA0[n] = dA0[(n - 1) >> 1] * dA0[n >> 1];
                dA1[n] = dA1[(n - 1) >> 1] * dA1[n >> 1];
            }
            #pragma unroll
            for (int n = 0; n < 16; n++) {
                h0[n] = dA0[n] * h0[n] + duA * rowA[8 + n];
                h1[n] = dA1[n] * h1[n] + duB * rowB[8 + n];
            }
        }
    } else {
        float Av[16];
        #pragma unroll
        for (int n = 0; n < 16; n++) Av[n] = -__expf(A_log[d * 16 + n]);
        for (int t = 0; t < CHL; t++, rowA += 40, rowB += 40, upA += 256, upB += 256) {
            float accA = bias, accB = bias;
            #pragma unroll
            for (int j = 0; j < 8; j++) { accA += rowA[j] * w8[j]; accB += rowB[j] * w8[j]; }
            float dtA = softplus_f(accA), dtB = softplus_f(accB);
            float uA = __bfloat162float(*upA), uB = __bfloat162float(*upB);
            sdt0 += dtA; sdt1 += dtB;
            float duA = dtA * uA, duB = dtB * uB;
            #pragma unroll
            for (int n = 0; n < 16; n++) {
                h0[n] = __expf(dtA * Av[n]) * h0[n] + duA * rowA[8 + n];
                h1[n] = __expf(dtB * Av[n]) * h1[n] + duB * rowB[8 + n];
            }
        }
    }
    float* qp0 = q + (((size_t)b * NCH + ch0) * 256 + d) * 16;
    float* qp1 = qp0 + (size_t)256 * 16;
    #pragma unroll
    for (int n = 0; n < 16; n += 4) {
        *(float4*)(qp0 + n) = make_float4(h0[n], h0[n+1], h0[n+2], h0[n+3]);
        *(float4*)(qp1 + n) = make_float4(h1[n], h1[n+1], h1[n+2], h1[n+3]);
    }
    sdt_out[((size_t)b * NCH + ch0) * 256 + d] = sdt0;
    sdt_out[((size_t)b * NCH + ch0 + 1) * 256 + d] = sdt1;
}

// scan2: cross-chunk combine, 8x8 software-pipelined loads for MLP.
__global__ __launch_bounds__(256) void k_scan2(
    const float* __restrict__ A_log, const float* __restrict__ sdt_in,
    float* __restrict__ q)
{
    int idx = blockIdx.x * 256 + threadIdx.x;   // (b,d,n): 65536
    int n = idx & 15, d = (idx >> 4) & 255, b = idx >> 12;
    float Av = -__expf(A_log[d * 16 + n]);
    float h = 0.f;
    for (int g = 0; g < NCH / 8; g++) {
        float qv[8], sv[8];
        #pragma unroll
        for (int j = 0; j < 8; j++) {
            size_t base = ((size_t)(b * NCH + g * 8 + j) * 256 + d);
            qv[j] = q[base * 16 + n];
            sv[j] = sdt_in[base];
        }
        #pragma unroll
        for (int j = 0; j < 8; j++) {
            size_t base = ((size_t)(b * NCH + g * 8 + j) * 256 + d);
            float P = __expf(Av * sv[j]);
            q[base * 16 + n] = h;
            h = P * h + qv[j];
        }
    }
}

__global__ __launch_bounds__(256) void k_scan3(
    const bf16* __restrict__ ubf, const float* __restrict__ xdbl,
    const float* __restrict__ dtw, const float* __restrict__ dtb_,
    const float* __restrict__ a1s, const int* __restrict__ pwf,
    const float* __restrict__ A_log, const float* __restrict__ Dp,
    const float* __restrict__ q, const bf16* __restrict__ zbf,
    bf16* __restrict__ ybf)
{
    int blk = blockIdx.x;                 // b*(NCH/2) + cp
    int b = blk >> 5, cp = blk & 31;
    int ch0 = cp * 2;
    int d = threadIdx.x;

    float a1 = a1s[d];
    bool pw = pwf[d] != 0;
    float w8[8];
    #pragma unroll
    for (int j = 0; j < 8; j++) w8[j] = dtw[d * 8 + j];
    float bias = dtb_[d];
    float Dv = Dp[d];
    float h0[16], h1[16];
    const float* qp0 = q + (((size_t)b * NCH + ch0) * 256 + d) * 16;
    const float* qp1 = qp0 + (size_t)256 * 16;
    #pragma unroll
    for (int n = 0; n < 16; n += 4) {
        float4 v0 = *(const float4*)(qp0 + n);
        float4 v1 = *(const float4*)(qp1 + n);
        h0[n] = v0.x; h0[n+1] = v0.y; h0[n+2] = v0.z; h0[n+3] = v0.w;
        h1[n] = v1.x; h1[n+1] = v1.y; h1[n+2] = v1.z; h1[n+3] = v1.w;
    }

    size_t tokA = (size_t)b * TOK + ch0 * CHL;
    const float* rowA = xdbl + tokA * 40;
    const float* rowB = rowA + CHL * 40;
    const bf16* upA = ubf + tokA * 256 + d;
    const bf16* upB = upA + CHL * 256;
    const bf16* zpA = zbf + tokA * 256 + d;
    const bf16* zpB = zpA + CHL * 256;
    bf16* ypA = ybf + tokA * 256 + d;
    bf16* ypB = ypA + CHL * 256;

    if (pw) {
        for (int t = 0; t < CHL; t++, rowA += 40, rowB += 40, upA += 256, upB += 256,
                                      zpA += 256, zpB += 256, ypA += 256, ypB += 256) {
            float accA = bias, accB = bias;
            #pragma unroll
            for (int j = 0; j < 8; j++) { accA += rowA[j] * w8[j]; accB += rowB[j] * w8[j]; }
            float dtA = softplus_f(accA), dtB = softplus_f(accB);
            float uA = __bfloat162float(*upA), uB = __bfloat162float(*upB);
            float duA = dtA * uA, duB = dtB * uB;
            float dA0[16], dA1[16];
            dA0[0] = __expf(dtA * a1);
            dA1[0] = __expf(dtB * a1);
            #pragma unroll
            for (int n = 1; n < 16; n++) {
                dA0[n] = dA0[(n - 1) >> 1] * dA0[n >> 1];
                dA1[n] = dA1[(n - 1) >> 1] * dA1[n >> 1];
            }
            float yA = 0.f, yB = 0.f;
            #pragma unroll
            for (int n = 0; n < 16; n++) {
                h0[n] = dA0[n] * h0[n] + duA * rowA[8 + n];
                h1[n] = dA1[n] * h1[n] + duB * rowB[8 + n];
                yA += h0[n] * rowA[24 + n];
                yB += h1[n] * rowB[24 + n];
            }
            float zA = __bfloat162float(*zpA), zB = __bfloat162float(*zpB);
            float sA = __fdividef(zA, 1.f + __expf(-zA));
            float sB = __fdividef(zB, 1.f + __expf(-zB));
            *ypA = __float2bfloat16((yA + uA * Dv) * sA);
            *ypB = __float2bfloat16((yB + uB * Dv) * sB);
        }
    } else {
        float Av[16];
        #pragma unroll
        for (int n = 0; n < 16; n++) Av[n] = -__expf(A_log[d * 16 + n]);
        for (int t = 0; t < CHL; t++, rowA += 40, rowB += 40, upA += 256, upB += 256,
                                      zpA += 256, zpB += 256, ypA += 256, ypB += 256) {
            float accA = bias, accB = bias;
            #pragma unroll
            for (int j = 0; j < 8; j++) { accA += rowA[j] * w8[j]; accB += rowB[j] * w8[j]; }
            float dtA = softplus_f(accA), dtB = softplus_f(accB);
            float uA = __bfloat162float(*upA), uB = __bfloat162float(*upB);
            float duA = dtA * uA, duB = dtB * uB;
            float yA = 0.f, yB = 0.f;
            #pragma unroll
            for (int n = 0; n < 16; n++) {
                h0[n] = __expf(dtA * Av[n]) * h0[n] + duA * rowA[8 + n];
                h1[n] = __expf(dtB * Av[n]) * h1[n] + duB * rowB[8 + n];
                yA += h0[n] * rowA[24 + n];
                yB += h1[n] * rowB[24 + n];
            }
            float zA = __bfloat162float(*zpA), zB = __bfloat162float(*zpB);
            float sA = __fdividef(zA, 1.f + __expf(-zA));
            float sB = __fdividef(zB, 1.f + __expf(-zB));
            *ypA = __float2bfloat16((yA + uA * Dv) * sA);
            *ypB = __float2bfloat16((yB + uB * Dv) * sB);
        }
    }
}

// ---------------------------------------------------------------------------
// K7: head epilogue: out[b,p,c] = (hg[(b*32+c)*96+p] + hb[p]) * stdev + mean
// ---------------------------------------------------------------------------
__global__ __launch_bounds__(256) void k_head_ep(
    const float* __restrict__ hg, const float* __restrict__ hb,
    const float* __restrict__ means, const float* __restrict__ stdev,
    float* __restrict__ out)
{
    int i = blockIdx.x * 256 + threadIdx.x;
    if (i >= BATCH * PRED * NVARS) return;
    int c = i & 31;
    int p = (i >> 5) % PRED;
    int b = i / (PRED * NVARS);
    float v = hg[((size_t)b * NVARS + c) * PRED + p] + hb[p];
    out[i] = v * stdev[b * NVARS + c] + means[b * NVARS + c];
}

// ---------------------------------------------------------------------------
extern "C" void kernel_launch(void* const* d_in, const int* in_sizes, int n_in,
                              void* d_out, int out_size, void* d_ws, size_t ws_size,
                              hipStream_t stream)
{
    const float* x_enc   = (const float*)d_in[0];
    const float* patch_w = (const float*)d_in[4];
    const float* norm_w  = (const float*)d_in[5];
    const float* in_w    = (const float*)d_in[6];
    const float* conv_w  = (const float*)d_in[7];
    const float* conv_b  = (const float*)d_in[8];
    const float* xp_w    = (const float*)d_in[9];
    const float* dt_w    = (const float*)d_in[10];
    const float* dt_b    = (const float*)d_in[11];
    const float* A_log   = (const float*)d_in[12];
    const float* D_skip  = (const float*)d_in[13];
    const float* out_w   = (const float*)d_in[14];
    const float* fnorm_w = (const float*)d_in[15];
    const float* head_w  = (const float*)d_in[16];
    const float* head_b  = (const float*)d_in[17];
    float* out = (float*)d_out;

    float* ws    = (float*)d_ws;
    float* means = ws;                          // 512
    float* stdv  = ws + 512;                    // 512
    float* x     = ws + 1024;                   // NTOK*128 f32   8MB
    float* xdbl  = x    + (size_t)NTOK * 128;   // NTOK*40      2.6MB
    float* qbuf  = xdbl + (size_t)NTOK * 40;    // 16*64*256*16  16.8MB
    float* sbuf  = qbuf + (size_t)BATCH * NCH * DIN * DSTATE;  // 1MB
    float* hg    = sbuf + (size_t)BATCH * NCH * DIN;           // 512*96
    float* a1s   = hg + 512 * PRED;             // NLAYER*DIN
    int*   pwf   = (int*)(a1s + NLAYER * DIN);  // NLAYER*DIN
    bf16* hbf  = (bf16*)(pwf + NLAYER * DIN);   // NTOK*128   4MB
    bf16* xsbf = hbf + (size_t)NTOK * 128;      // NTOK*256   8MB
    bf16* zbf  = xsbf + (size_t)NTOK * 256;     // NTOK*256   8MB
    bf16* ubf  = zbf + (size_t)NTOK * 256;      // NTOK*256   8MB
    bf16* ybf  = ubf + (size_t)NTOK * 256;      // NTOK*256   8MB
    bf16* wbf  = ybf + (size_t)NTOK * 256;      // 610304     1.2MB

    const int NIW = NLAYER * 2 * DIN * DMODEL;         // 131072
    const int NXW = NLAYER * (DTRANK + 2*DSTATE) * DIN;// 20480
    const int NOW = NLAYER * DMODEL * DIN;             // 65536
    const int NHW = PRED * LTOK * DMODEL;              // 393216
    bf16* iwbf = wbf;
    bf16* xwbf = iwbf + NIW;
    bf16* owbf = xwbf + NXW;
    bf16* hwbf = owbf + NOW;

    k_cast<<<(NIW + NXW + NOW + NHW + 255) / 256, 256, 0, stream>>>(
        in_w, xp_w, out_w, head_w, NIW, NXW, NOW, NHW, wbf);
    k_prep<<<2, 256, 0, stream>>>(A_log, a1s, pwf);

    k_instnorm_patch<<<BATCH * NVARS, 256, 0, stream>>>(x_enc, patch_w, x, means, stdv);

    for (int layer = 0; layer < NLAYER; layer++) {
        const float* nw  = norm_w + layer * DMODEL;
        const float* cw  = conv_w + layer * DIN * DCONV;
        const float* cb  = conv_b + layer * DIN;
        const float* dw  = dt_w   + layer * DIN * DTRANK;
        const float* db  = dt_b   + layer * DIN;
        const float* al  = A_log  + layer * DIN * DSTATE;
        const float* dp  = D_skip + layer * DIN;
        const float* a1l = a1s + layer * DIN;
        const int*   pwl = pwf + layer * DIN;
        const bf16* iw = iwbf + (size_t)layer * 2 * DIN * DMODEL;
        const bf16* xw = xwbf + (size_t)layer * (DTRANK + 2 * DSTATE) * DIN;
        const bf16* ow = owbf + (size_t)layer * DMODEL * DIN;

        k_rmsnorm<<<NTOK / 4, 256, 0, stream>>>(x, nw, hbf);
        // xz = h @ in_w^T, split: cols 0..255 -> xsbf, 256..511 -> zbf (bf16)
        mfma_gemm<3><<<dim3(4, NTOK / 128, 1), 256, 0, stream>>>(
            hbf, iw, nullptr, zbf, xsbf, NTOK, 512, DMODEL, DMODEL, DMODEL);
        k_conv<<<(NTOK * DIN) / 256, 256, 0, stream>>>(xsbf, cw, cb, ubf);
        // xdbl = u @ xp_w^T
        mfma_gemm<0><<<dim3(1, NTOK / 128, 1), 256, 0, stream>>>(
            ubf, xw, xdbl, nullptr, nullptr, NTOK, DTRANK + 2 * DSTATE, DIN, DIN, DIN);
        k_scan1<<<BATCH * NCH / 2, 256, 0, stream>>>(ubf, xdbl, dw, db, a1l, pwl, al, qbuf, sbuf);
        k_scan2<<<(BATCH * DIN * DSTATE) / 256, 256, 0, stream>>>(al, sbuf, qbuf);
        k_scan3<<<BATCH * NCH / 2, 256, 0, stream>>>(ubf, xdbl, dw, db, a1l, pwl, al, dp, qbuf, zbf, ybf);
        // x += y @ out_w^T  (split-K=2, atomicAdd into residual)
        mfma_gemm<2><<<dim3(1, NTOK / 128, 2), 256, 0, stream>>>(
            ybf, ow, x, nullptr, nullptr, NTOK, DMODEL, DIN, DIN, DIN / 2);
    }

    // final norm -> hbf; head = split-K MFMA into zeroed hg, then epilogue
    k_rmsnorm<<<NTOK / 4, 256, 0, stream>>>(x, fnorm_w, hbf);
    hipMemsetAsync(hg, 0, 512 * PRED * sizeof(float), stream);
    mfma_gemm<2><<<dim3(1, 4, 32), 256, 0, stream>>>(
        hbf, hwbf, hg, nullptr, nullptr, 512, PRED, LTOK * DMODEL, LTOK * DMODEL, 128);
    k_head_ep<<<(BATCH * PRED * NVARS + 255) / 256, 256, 0, stream>>>(
        hg, head_b, means, stdv, out);
}

// Round 8
// 207.043 us; speedup vs baseline: 1.4393x; 1.3065x over previous
//
#include <hip/hip_runtime.h>
#include <hip/hip_bf16.h>
#include <math.h>

#define BATCH   16
#define SEQL    512
#define NVARS   32
#define PATCHL  16
#define LTOK    32
#define DMODEL  128
#define NLAYER  2
#define DIN     256
#define DSTATE  16
#define DTRANK  8
#define DCONV   4
#define PRED    96
#define TOK     1024
#define NTOK    (BATCH*TOK)   // 16384
#define EPSF    1e-5f
#define NCH     64            // time chunks
#define CHL     16            // TOK/NCH

typedef __attribute__((ext_vector_type(8))) short bf16x8;
typedef __attribute__((ext_vector_type(4))) float f32x4;
typedef __hip_bfloat16 bf16;

// ---------------------------------------------------------------------------
// K0: cast all GEMM weights to bf16 + (tail range) per-(layer,d) scan consts
// ---------------------------------------------------------------------------
__global__ __launch_bounds__(256) void k_cast(
    const float* __restrict__ a, const float* __restrict__ b,
    const float* __restrict__ c, const float* __restrict__ d,
    int na, int nb, int nc, int nd, bf16* __restrict__ out,
    const float* __restrict__ A_log, float* __restrict__ a1s, int* __restrict__ pwf)
{
    int i = blockIdx.x * 256 + threadIdx.x;
    int total = na + nb + nc + nd;
    if (i < total) {
        float v;
        if (i < na) v = a[i];
        else if (i < na + nb) v = b[i - na];
        else if (i < na + nb + nc) v = c[i - na - nb];
        else v = d[i - na - nb - nc];
        out[i] = __float2bfloat16(v);
    } else if (i < total + NLAYER * DIN) {
        int j = i - total;
        const float* al = A_log + (size_t)j * DSTATE;
        float a1 = -__expf(al[0]);
        bool pw = true;
        #pragma unroll
        for (int n = 1; n < 16; n++) {
            float av = -__expf(al[n]);
            pw = pw && (fabsf(av - (n + 1) * a1) <= 1e-5f * fabsf((n + 1) * a1));
        }
        a1s[j] = a1;
        pwf[j] = pw ? 1 : 0;
    }
}

// ---------------------------------------------------------------------------
// K1: per-(b,c) instance norm over time + patch embedding
// ---------------------------------------------------------------------------
__global__ __launch_bounds__(256) void k_instnorm_patch(
    const float* __restrict__ x_enc, const float* __restrict__ patch_w,
    float* __restrict__ x, float* __restrict__ means, float* __restrict__ stdev)
{
    int bc = blockIdx.x;
    int b = bc >> 5, c = bc & 31;
    __shared__ float xe[SEQL];
    __shared__ float pw[DMODEL * PATCHL];
    __shared__ float red[8];
    int tid = threadIdx.x;

    float v0 = x_enc[((size_t)b * SEQL + tid) * NVARS + c];
    float v1 = x_enc[((size_t)b * SEQL + tid + 256) * NVARS + c];
    for (int i = tid; i < DMODEL * PATCHL; i += 256) pw[i] = patch_w[i];

    float s = v0 + v1;
    for (int o = 1; o < 64; o <<= 1) s += __shfl_xor(s, o, 64);
    if ((tid & 63) == 0) red[tid >> 6] = s;
    __syncthreads();
    float mean = (red[0] + red[1] + red[2] + red[3]) * (1.f / 512.f);

    float d0 = v0 - mean, d1 = v1 - mean;
    float q = d0 * d0 + d1 * d1;
    for (int o = 1; o < 64; o <<= 1) q += __shfl_xor(q, o, 64);
    if ((tid & 63) == 0) red[4 + (tid >> 6)] = q;
    __syncthreads();
    float var = (red[4] + red[5] + red[6] + red[7]) * (1.f / 512.f);
    float sd = sqrtf(var + EPSF);
    float rsd = 1.f / sd;
    if (tid == 0) { means[bc] = mean; stdev[bc] = sd; }

    xe[tid] = d0 * rsd;
    xe[tid + 256] = d1 * rsd;
    __syncthreads();

    size_t base = ((size_t)b * TOK + (size_t)c * LTOK) * DMODEL;
    for (int o = tid; o < LTOK * DMODEL; o += 256) {
        int l = o >> 7, dm = o & 127;
        float acc = 0.f;
        #pragma unroll
        for (int p = 0; p < PATCHL; p++) acc += xe[l * PATCHL + p] * pw[dm * PATCHL + p];
        x[base + o] = acc;
    }
}

// ---------------------------------------------------------------------------
// K2: RMSNorm over last dim (128), bf16 output. One wave per token.
// ---------------------------------------------------------------------------
__global__ __launch_bounds__(256) void k_rmsnorm(
    const float* __restrict__ in, const float* __restrict__ w,
    bf16* __restrict__ out)
{
    int wave = threadIdx.x >> 6, lane = threadIdx.x & 63;
    int tok = blockIdx.x * 4 + wave;
    const float* r = in + (size_t)tok * DMODEL;
    float a = r[lane], bv = r[lane + 64];
    float q = a * a + bv * bv;
    for (int o = 1; o < 64; o <<= 1) q += __shfl_xor(q, o, 64);
    float rms = rsqrtf(q * (1.f / DMODEL) + EPSF);
    bf16* o_ = out + (size_t)tok * DMODEL;
    o_[lane]      = __float2bfloat16(a  * rms * w[lane]);
    o_[lane + 64] = __float2bfloat16(bv * rms * w[lane + 64]);
}

// ---------------------------------------------------------------------------
// K3: MFMA bf16 GEMM.  C op= A[M,K](lda) @ W[N,K]^T  (f32 accum)
// 128x128 tile, BK=32, 4 waves (2x2), 16 MFMA(16x16x32)/wave/K-step.
// MODE: 0=store f32 C, 2=atomicAdd f32 C, 3=split bf16 (n<256 -> C3, else C2).
// ---------------------------------------------------------------------------
template <int MODE>
__global__ __launch_bounds__(256) void mfma_gemm(
    const bf16* __restrict__ A, const bf16* __restrict__ W,
    float* __restrict__ C, bf16* __restrict__ C2, bf16* __restrict__ C3,
    int M, int N, int K, int lda, int kper)
{
    __shared__ ushort Asm[128][40];
    __shared__ ushort Wsm[128][40];
    int bm = blockIdx.y * 128, bn = blockIdx.x * 128;
    int tid = threadIdx.x;
    int w = tid >> 6, l = tid & 63;
    int wr = w >> 1, wc = w & 1;
    int kb = (l >> 4) * 8, lr = l & 15;

    f32x4 acc[4][4];
    #pragma unroll
    for (int i = 0; i < 4; i++)
        #pragma unroll
        for (int j = 0; j < 4; j++) acc[i][j] = (f32x4){0.f, 0.f, 0.f, 0.f};

    int kbeg = blockIdx.z * kper;
    for (int k0 = kbeg; k0 < kbeg + kper; k0 += 32) {
        #pragma unroll
        for (int i = 0; i < 2; i++) {
            int idx = tid + 256 * i;
            int row = idx >> 2, kq = (idx & 3) * 8;
            *(float4*)&Asm[row][kq] =
                *(const float4*)&A[(size_t)(bm + row) * lda + k0 + kq];
            float4 wv = make_float4(0.f, 0.f, 0.f, 0.f);
            if (bn + row < N)
                wv = *(const float4*)&W[(size_t)(bn + row) * K + k0 + kq];
            *(float4*)&Wsm[row][kq] = wv;
        }
        __syncthreads();
        bf16x8 af[4], bfr[4];
        #pragma unroll
        for (int f = 0; f < 4; f++) {
            af[f]  = *(const bf16x8*)&Asm[wr * 64 + f * 16 + lr][kb];
            bfr[f] = *(const bf16x8*)&Wsm[wc * 64 + f * 16 + lr][kb];
        }
        #pragma unroll
        for (int mf = 0; mf < 4; mf++)
            #pragma unroll
            for (int nf = 0; nf < 4; nf++)
                acc[mf][nf] = __builtin_amdgcn_mfma_f32_16x16x32_bf16(
                    af[mf], bfr[nf], acc[mf][nf], 0, 0, 0);
        __syncthreads();
    }

    // C/D layout: col = lane&15, row = (lane>>4)*4 + reg
    int rbase = bm + wr * 64 + (l >> 4) * 4;
    int cbase = bn + wc * 64 + lr;
    #pragma unroll
    for (int mf = 0; mf < 4; mf++) {
        #pragma unroll
        for (int nf = 0; nf < 4; nf++) {
            int n = cbase + nf * 16;
            if (n >= N) continue;
            #pragma unroll
            for (int r = 0; r < 4; r++) {
                int m = rbase + mf * 16 + r;
                float v = acc[mf][nf][r];
                if (MODE == 0) C[(size_t)m * N + n] = v;
                else if (MODE == 2) atomicAdd(&C[(size_t)m * N + n], v);
                else {
                    if (n < 256) C3[(size_t)m * 256 + n] = __float2bfloat16(v);
                    else C2[(size_t)m * 256 + (n - 256)] = __float2bfloat16(v);
                }
            }
        }
    }
}

// ---------------------------------------------------------------------------
// K4: fused conv(k=4,causal)+bias+SiLU AND x_proj MFMA.
// Block = (b, ch): 16 tokens. Phase A: u (regs+LDS+global). Phase B: 3 waves
// compute xdbl[16 tok][40] = u @ xw^T via MFMA 16x16x32, K=256.
// ---------------------------------------------------------------------------
__global__ __launch_bounds__(256) void k_convx(
    const bf16* __restrict__ xs, const float* __restrict__ cw,
    const float* __restrict__ cb, const bf16* __restrict__ xw,
    bf16* __restrict__ ubf, float* __restrict__ xdbl)
{
    int blk = blockIdx.x;              // b*NCH + ch
    int b = blk >> 6, ch = blk & (NCH - 1);
    int d = threadIdx.x;
    __shared__ ushort u_lds[16][264];

    // ---- phase A: depthwise conv + silu for 16 tokens, channel d ----
    float c0 = cw[d * 4], c1 = cw[d * 4 + 1], c2 = cw[d * 4 + 2], c3 = cw[d * 4 + 3];
    float cbias = cb[d];
    int tloc0 = ch * CHL;
    const bf16* col = xs + ((size_t)b * TOK + tloc0) * 256 + d;
    float xv[19];
    #pragma unroll
    for (int i = 0; i < 19; i++) {
        int tg = tloc0 - 3 + i;
        xv[i] = (tg >= 0) ? __bfloat162float(col[(size_t)(i - 3) * 256]) : 0.f;
    }
    bf16* uout = ubf + ((size_t)b * TOK + tloc0) * 256 + d;
    #pragma unroll
    for (int t = 0; t < 16; t++) {
        float a = cbias + xv[t] * c0 + xv[t + 1] * c1 + xv[t + 2] * c2 + xv[t + 3] * c3;
        float s = __fdividef(a, 1.f + __expf(-a));
        bf16 ub = __float2bfloat16(s);
        u_lds[t][d] = *(ushort*)&ub;
        uout[(size_t)t * 256] = ub;
    }
    __syncthreads();

    // ---- phase B: xdbl = u @ xw^T  (M=16 tokens, N=40, K=256) ----
    int w = threadIdx.x >> 6, l = threadIdx.x & 63;
    if (w < 3) {
        int lr = l & 15, kb = (l >> 4) * 8;
        int nrow = w * 16 + lr;
        bool valid = nrow < 40;
        const bf16* wrow = xw + (size_t)nrow * 256;
        f32x4 acc = (f32x4){0.f, 0.f, 0.f, 0.f};
        #pragma unroll
        for (int ks = 0; ks < 8; ks++) {
            bf16x8 af = *(const bf16x8*)&u_lds[lr][ks * 32 + kb];
            bf16x8 bfr = (bf16x8){0, 0, 0, 0, 0, 0, 0, 0};
            if (valid) bfr = *(const bf16x8*)&wrow[ks * 32 + kb];
            acc = __builtin_amdgcn_mfma_f32_16x16x32_bf16(af, bfr, acc, 0, 0, 0);
        }
        // C/D: col = lane&15 (n), row = (lane>>4)*4 + reg (token)
        int ncol = w * 16 + (l & 15);
        if (ncol < 40) {
            #pragma unroll
            for (int r = 0; r < 4; r++) {
                int t = (l >> 4) * 4 + r;
                xdbl[((size_t)b * TOK + tloc0 + t) * 40 + ncol] = acc[r];
            }
        }
    }
}

// ---------------------------------------------------------------------------
// Scan, chunked 3-phase (NCH=64, CHL=16), R5-proven bodies.
// qbuf layout: [b][ch][n][d] -> every access coalesced in d.
// ---------------------------------------------------------------------------
__device__ __forceinline__ float softplus_f(float x) {
    return (x > 8.f) ? x : __logf(1.f + __expf(x));
}

__global__ __launch_bounds__(256) void k_scan1(
    const bf16* __restrict__ ubf, const float* __restrict__ xdbl,
    const float* __restrict__ dtw, const float* __restrict__ dtb_,
    const float* __restrict__ a1s, const int* __restrict__ pwf,
    const float* __restrict__ A_log,
    float* __restrict__ q, float* __restrict__ sdt_out)
{
    int blk = blockIdx.x;                 // b*NCH + ch
    int b = blk >> 6, ch = blk & (NCH - 1);
    int d = threadIdx.x;

    float a1 = a1s[d];
    bool pw = pwf[d] != 0;
    float w8[8];
    #pragma unroll
    for (int j = 0; j < 8; j++) w8[j] = dtw[d * 8 + j];
    float bias = dtb_[d];
    float h[16];
    #pragma unroll
    for (int n = 0; n < 16; n++) h[n] = 0.f;
    float sdt = 0.f;

    size_t tok0 = (size_t)b * TOK + ch * CHL;
    const float* row = xdbl + tok0 * 40;
    const bf16* up = ubf + tok0 * 256 + d;

    if (pw) {
        for (int t = 0; t < CHL; t++, row += 40, up += 256) {
            float acc = bias;
            #pragma unroll
            for (int j = 0; j < 8; j++) acc += row[j] * w8[j];
            float dtv = softplus_f(acc);
            float uu = __bfloat162float(*up);
            sdt += dtv;
            float du = dtv * uu;
            float dA[16];
            dA[0] = __expf(dtv * a1);
            #pragma unroll
            for (int n = 1; n < 16; n++) dA[n] = dA[(n - 1) >> 1] * dA[n >> 1];
            #pragma unroll
            for (int n = 0; n < 16; n++)
                h[n] = dA[n] * h[n] + du * row[8 + n];
        }
    } else {
        float Av[16];
        #pragma unroll
        for (int n = 0; n < 16; n++) Av[n] = -__expf(A_log[d * 16 + n]);
        for (int t = 0; t < CHL; t++, row += 40, up += 256) {
            float acc = bias;
            #pragma unroll
            for (int j = 0; j < 8; j++) acc += row[j] * w8[j];
            float dtv = softplus_f(acc);
            float uu = __bfloat162float(*up);
            sdt += dtv;
            float du = dtv * uu;
            #pragma unroll
            for (int n = 0; n < 16; n++)
                h[n] = __expf(dtv * Av[n]) * h[n] + du * row[8 + n];
        }
    }
    // q[b][ch][n][d]
    float* qp = q + ((size_t)blk * 16) * 256 + d;
    #pragma unroll
    for (int n = 0; n < 16; n++) qp[(size_t)n * 256] = h[n];
    sdt_out[(size_t)blk * 256 + d] = sdt;
}

// scan2: cross-chunk combine; thread = (b,n,d), d fastest -> coalesced.
__global__ __launch_bounds__(256) void k_scan2(
    const float* __restrict__ A_log, const float* __restrict__ sdt_in,
    float* __restrict__ q)
{
    int idx = blockIdx.x * 256 + threadIdx.x;   // 65536
    int d = idx & 255, n = (idx >> 8) & 15, b = idx >> 12;
    float Av = -__expf(A_log[d * 16 + n]);
    float h = 0.f;
    for (int g = 0; g < NCH / 8; g++) {
        float qv[8], sv[8];
        #pragma unroll
        for (int j = 0; j < 8; j++) {
            size_t blk = (size_t)b * NCH + g * 8 + j;
            qv[j] = q[(blk * 16 + n) * 256 + d];
            sv[j] = sdt_in[blk * 256 + d];
        }
        #pragma unroll
        for (int j = 0; j < 8; j++) {
            size_t blk = (size_t)b * NCH + g * 8 + j;
            float P = __expf(Av * sv[j]);
            q[(blk * 16 + n) * 256 + d] = h;
            h = P * h + qv[j];
        }
    }
}

__global__ __launch_bounds__(256) void k_scan3(
    const bf16* __restrict__ ubf, const float* __restrict__ xdbl,
    const float* __restrict__ dtw, const float* __restrict__ dtb_,
    const float* __restrict__ a1s, const int* __restrict__ pwf,
    const float* __restrict__ A_log, const float* __restrict__ Dp,
    const float* __restrict__ q, const bf16* __restrict__ zbf,
    bf16* __restrict__ ybf)
{
    int blk = blockIdx.x;
    int b = blk >> 6, ch = blk & (NCH - 1);
    int d = threadIdx.x;

    float a1 = a1s[d];
    bool pw = pwf[d] != 0;
    float w8[8];
    #pragma unroll
    for (int j = 0; j < 8; j++) w8[j] = dtw[d * 8 + j];
    float bias = dtb_[d];
    float Dv = Dp[d];
    float h[16];
    const float* qp = q + ((size_t)blk * 16) * 256 + d;
    #pragma unroll
    for (int n = 0; n < 16; n++) h[n] = qp[(size_t)n * 256];

    size_t tok0 = (size_t)b * TOK + ch * CHL;
    const float* row = xdbl + tok0 * 40;
    const bf16* up = ubf + tok0 * 256 + d;
    const bf16* zp = zbf + tok0 * 256 + d;
    bf16* yp = ybf + tok0 * 256 + d;

    if (pw) {
        for (int t = 0; t < CHL; t++, row += 40, up += 256, zp += 256, yp += 256) {
            float acc = bias;
            #pragma unroll
            for (int j = 0; j < 8; j++) acc += row[j] * w8[j];
            float dtv = softplus_f(acc);
            float uu = __bfloat162float(*up);
            float du = dtv * uu;
            float dA[16];
            dA[0] = __expf(dtv * a1);
            #pragma unroll
            for (int n = 1; n < 16; n++) dA[n] = dA[(n - 1) >> 1] * dA[n >> 1];
            float ya = 0.f;
            #pragma unroll
            for (int n = 0; n < 16; n++) {
                h[n] = dA[n] * h[n] + du * row[8 + n];
                ya += h[n] * row[24 + n];
            }
            float zv = __bfloat162float(*zp);
            float sz = __fdividef(zv, 1.f + __expf(-zv));
            *yp = __float2bfloat16((ya + uu * Dv) * sz);
        }
    } else {
        float Av[16];
        #pragma unroll
        for (int n = 0; n < 16; n++) Av[n] = -__expf(A_log[d * 16 + n]);
        for (int t = 0; t < CHL; t++, row += 40, up += 256, zp += 256, yp += 256) {
            float acc = bias;
            #pragma unroll
            for (int j = 0; j < 8; j++) acc += row[j] * w8[j];
            float dtv = softplus_f(acc);
            float uu = __bfloat162float(*up);
            float du = dtv * uu;
            float ya = 0.f;
            #pragma unroll
            for (int n = 0; n < 16; n++) {
                h[n] = __expf(dtv * Av[n]) * h[n] + du * row[8 + n];
                ya += h[n] * row[24 + n];
            }
            float zv = __bfloat162float(*zp);
            float sz = __fdividef(zv, 1.f + __expf(-zv));
            *yp = __float2bfloat16((ya + uu * Dv) * sz);
        }
    }
}

// ---------------------------------------------------------------------------
// K7: head epilogue
// ---------------------------------------------------------------------------
__global__ __launch_bounds__(256) void k_head_ep(
    const float* __restrict__ hg, const float* __restrict__ hb,
    const float* __restrict__ means, const float* __restrict__ stdev,
    float* __restrict__ out)
{
    int i = blockIdx.x * 256 + threadIdx.x;
    if (i >= BATCH * PRED * NVARS) return;
    int c = i & 31;
    int p = (i >> 5) % PRED;
    int b = i / (PRED * NVARS);
    float v = hg[((size_t)b * NVARS + c) * PRED + p] + hb[p];
    out[i] = v * stdev[b * NVARS + c] + means[b * NVARS + c];
}

// ---------------------------------------------------------------------------
extern "C" void kernel_launch(void* const* d_in, const int* in_sizes, int n_in,
                              void* d_out, int out_size, void* d_ws, size_t ws_size,
                              hipStream_t stream)
{
    const float* x_enc   = (const float*)d_in[0];
    const float* patch_w = (const float*)d_in[4];
    const float* norm_w  = (const float*)d_in[5];
    const float* in_w    = (const float*)d_in[6];
    const float* conv_w  = (const float*)d_in[7];
    const float* conv_b  = (const float*)d_in[8];
    const float* xp_w    = (const float*)d_in[9];
    const float* dt_w    = (const float*)d_in[10];
    const float* dt_b    = (const float*)d_in[11];
    const float* A_log   = (const float*)d_in[12];
    const float* D_skip  = (const float*)d_in[13];
    const float* out_w   = (const float*)d_in[14];
    const float* fnorm_w = (const float*)d_in[15];
    const float* head_w  = (const float*)d_in[16];
    const float* head_b  = (const float*)d_in[17];
    float* out = (float*)d_out;

    float* ws    = (float*)d_ws;
    float* means = ws;                          // 512
    float* stdv  = ws + 512;                    // 512
    float* x     = ws + 1024;                   // NTOK*128 f32   8MB
    float* xdbl  = x    + (size_t)NTOK * 128;   // NTOK*40      2.6MB
    float* qbuf  = xdbl + (size_t)NTOK * 40;    // 16*64*16*256  16.8MB
    float* sbuf  = qbuf + (size_t)BATCH * NCH * DIN * DSTATE;  // 1MB
    float* hg    = sbuf + (size_t)BATCH * NCH * DIN;           // 512*96
    float* a1s   = hg + 512 * PRED;             // NLAYER*DIN
    int*   pwf   = (int*)(a1s + NLAYER * DIN);  // NLAYER*DIN
    bf16* hbf  = (bf16*)(pwf + NLAYER * DIN);   // NTOK*128   4MB
    bf16* xsbf = hbf + (size_t)NTOK * 128;      // NTOK*256   8MB
    bf16* zbf  = xsbf + (size_t)NTOK * 256;     // NTOK*256   8MB
    bf16* ubf  = zbf + (size_t)NTOK * 256;      // NTOK*256   8MB
    bf16* ybf  = ubf + (size_t)NTOK * 256;      // NTOK*256   8MB
    bf16* wbf  = ybf + (size_t)NTOK * 256;      // 610304     1.2MB

    const int NIW = NLAYER * 2 * DIN * DMODEL;         // 131072
    const int NXW = NLAYER * (DTRANK + 2*DSTATE) * DIN;// 20480
    const int NOW = NLAYER * DMODEL * DIN;             // 65536
    const int NHW = PRED * LTOK * DMODEL;              // 393216
    bf16* iwbf = wbf;
    bf16* xwbf = iwbf + NIW;
    bf16* owbf = xwbf + NXW;
    bf16* hwbf = owbf + NOW;

    k_cast<<<(NIW + NXW + NOW + NHW + NLAYER * DIN + 255) / 256, 256, 0, stream>>>(
        in_w, xp_w, out_w, head_w, NIW, NXW, NOW, NHW, wbf, A_log, a1s, pwf);

    k_instnorm_patch<<<BATCH * NVARS, 256, 0, stream>>>(x_enc, patch_w, x, means, stdv);

    for (int layer = 0; layer < NLAYER; layer++) {
        const float* nw  = norm_w + layer * DMODEL;
        const float* cw  = conv_w + layer * DIN * DCONV;
        const float* cb  = conv_b + layer * DIN;
        const float* dw  = dt_w   + layer * DIN * DTRANK;
        const float* db  = dt_b   + layer * DIN;
        const float* al  = A_log  + layer * DIN * DSTATE;
        const float* dp  = D_skip + layer * DIN;
        const float* a1l = a1s + layer * DIN;
        const int*   pwl = pwf + layer * DIN;
        const bf16* iw = iwbf + (size_t)layer * 2 * DIN * DMODEL;
        const bf16* xw = xwbf + (size_t)layer * (DTRANK + 2 * DSTATE) * DIN;
        const bf16* ow = owbf + (size_t)layer * DMODEL * DIN;

        k_rmsnorm<<<NTOK / 4, 256, 0, stream>>>(x, nw, hbf);
        // xz = h @ in_w^T, split: cols 0..255 -> xsbf, 256..511 -> zbf
        mfma_gemm<3><<<dim3(4, NTOK / 128, 1), 256, 0, stream>>>(
            hbf, iw, nullptr, zbf, xsbf, NTOK, 512, DMODEL, DMODEL, DMODEL);
        // fused conv + x_proj
        k_convx<<<BATCH * NCH, 256, 0, stream>>>(xsbf, cw, cb, xw, ubf, xdbl);
        k_scan1<<<BATCH * NCH, 256, 0, stream>>>(ubf, xdbl, dw, db, a1l, pwl, al, qbuf, sbuf);
        k_scan2<<<(BATCH * DIN * DSTATE) / 256, 256, 0, stream>>>(al, sbuf, qbuf);
        k_scan3<<<BATCH * NCH, 256, 0, stream>>>(ubf, xdbl, dw, db, a1l, pwl, al, dp, qbuf, zbf, ybf);
        // x += y @ out_w^T  (split-K=2, atomicAdd into residual)
        mfma_gemm<2><<<dim3(1, NTOK / 128, 2), 256, 0, stream>>>(
            ybf, ow, x, nullptr, nullptr, NTOK, DMODEL, DIN, DIN, DIN / 2);
    }

    // final norm -> hbf; head = split-K MFMA into zeroed hg, then epilogue
    k_rmsnorm<<<NTOK / 4, 256, 0, stream>>>(x, fnorm_w, hbf);
    hipMemsetAsync(hg, 0, 512 * PRED * sizeof(float), stream);
    mfma_gemm<2><<<dim3(1, 4, 32), 256, 0, stream>>>(
        hbf, hwbf, hg, nullptr, nullptr, 512, PRED, LTOK * DMODEL, LTOK * DMODEL, 128);
    k_head_ep<<<(BATCH * PRED * NVARS + 255) / 256, 256, 0, stream>>>(
        hg, head_b, means, stdv, out);
}

// Round 9
// 172.282 us; speedup vs baseline: 1.7297x; 1.2018x over previous
//
#include <hip/hip_runtime.h>
#include <hip/hip_bf16.h>
#include <math.h>

#define BATCH   16
#define SEQL    512
#define NVARS   32
#define PATCHL  16
#define LTOK    32
#define DMODEL  128
#define NLAYER  2
#define DIN     256
#define DSTATE  16
#define DTRANK  8
#define DCONV   4
#define PRED    96
#define TOK     1024
#define NTOK    (BATCH*TOK)   // 16384
#define EPSF    1e-5f
#define NCH     64            // time chunks
#define CHL     16            // TOK/NCH

typedef __attribute__((ext_vector_type(8))) short bf16x8;
typedef __attribute__((ext_vector_type(4))) float f32x4;
typedef __hip_bfloat16 bf16;

// ---------------------------------------------------------------------------
// K0: cast weights to bf16 + scan consts + zero hg (all one grid)
// ---------------------------------------------------------------------------
__global__ __launch_bounds__(256) void k_cast(
    const float* __restrict__ a, const float* __restrict__ b,
    const float* __restrict__ c, const float* __restrict__ d,
    int na, int nb, int nc, int nd, bf16* __restrict__ out,
    const float* __restrict__ A_log, float* __restrict__ a1s, int* __restrict__ pwf,
    float* __restrict__ hg)
{
    int i = blockIdx.x * 256 + threadIdx.x;
    int total = na + nb + nc + nd;
    if (i < total) {
        float v;
        if (i < na) v = a[i];
        else if (i < na + nb) v = b[i - na];
        else if (i < na + nb + nc) v = c[i - na - nb];
        else v = d[i - na - nb - nc];
        out[i] = __float2bfloat16(v);
    } else if (i < total + NLAYER * DIN) {
        int j = i - total;
        const float* al = A_log + (size_t)j * DSTATE;
        float a1 = -__expf(al[0]);
        bool pw = true;
        #pragma unroll
        for (int n = 1; n < 16; n++) {
            float av = -__expf(al[n]);
            pw = pw && (fabsf(av - (n + 1) * a1) <= 1e-5f * fabsf((n + 1) * a1));
        }
        a1s[j] = a1;
        pwf[j] = pw ? 1 : 0;
    } else if (i < total + NLAYER * DIN + 512 * PRED) {
        hg[i - total - NLAYER * DIN] = 0.f;
    }
}

// ---------------------------------------------------------------------------
// K1: per-(b,c) instance norm over time + patch embedding
// ---------------------------------------------------------------------------
__global__ __launch_bounds__(256) void k_instnorm_patch(
    const float* __restrict__ x_enc, const float* __restrict__ patch_w,
    float* __restrict__ x, float* __restrict__ means, float* __restrict__ stdev)
{
    int bc = blockIdx.x;
    int b = bc >> 5, c = bc & 31;
    __shared__ float xe[SEQL];
    __shared__ float pw[DMODEL * PATCHL];
    __shared__ float red[8];
    int tid = threadIdx.x;

    float v0 = x_enc[((size_t)b * SEQL + tid) * NVARS + c];
    float v1 = x_enc[((size_t)b * SEQL + tid + 256) * NVARS + c];
    for (int i = tid; i < DMODEL * PATCHL; i += 256) pw[i] = patch_w[i];

    float s = v0 + v1;
    for (int o = 1; o < 64; o <<= 1) s += __shfl_xor(s, o, 64);
    if ((tid & 63) == 0) red[tid >> 6] = s;
    __syncthreads();
    float mean = (red[0] + red[1] + red[2] + red[3]) * (1.f / 512.f);

    float d0 = v0 - mean, d1 = v1 - mean;
    float q = d0 * d0 + d1 * d1;
    for (int o = 1; o < 64; o <<= 1) q += __shfl_xor(q, o, 64);
    if ((tid & 63) == 0) red[4 + (tid >> 6)] = q;
    __syncthreads();
    float var = (red[4] + red[5] + red[6] + red[7]) * (1.f / 512.f);
    float sd = sqrtf(var + EPSF);
    float rsd = 1.f / sd;
    if (tid == 0) { means[bc] = mean; stdev[bc] = sd; }

    xe[tid] = d0 * rsd;
    xe[tid + 256] = d1 * rsd;
    __syncthreads();

    size_t base = ((size_t)b * TOK + (size_t)c * LTOK) * DMODEL;
    for (int o = tid; o < LTOK * DMODEL; o += 256) {
        int l = o >> 7, dm = o & 127;
        float acc = 0.f;
        #pragma unroll
        for (int p = 0; p < PATCHL; p++) acc += xe[l * PATCHL + p] * pw[dm * PATCHL + p];
        x[base + o] = acc;
    }
}

// ---------------------------------------------------------------------------
// K2: RMSNorm over last dim (128), bf16 output. One wave per token.
// ---------------------------------------------------------------------------
__global__ __launch_bounds__(256) void k_rmsnorm(
    const float* __restrict__ in, const float* __restrict__ w,
    bf16* __restrict__ out)
{
    int wave = threadIdx.x >> 6, lane = threadIdx.x & 63;
    int tok = blockIdx.x * 4 + wave;
    const float* r = in + (size_t)tok * DMODEL;
    float a = r[lane], bv = r[lane + 64];
    float q = a * a + bv * bv;
    for (int o = 1; o < 64; o <<= 1) q += __shfl_xor(q, o, 64);
    float rms = rsqrtf(q * (1.f / DMODEL) + EPSF);
    bf16* o_ = out + (size_t)tok * DMODEL;
    o_[lane]      = __float2bfloat16(a  * rms * w[lane]);
    o_[lane + 64] = __float2bfloat16(bv * rms * w[lane + 64]);
}

// ---------------------------------------------------------------------------
// K3: MFMA bf16 GEMM.  C op= A[M,K](lda) @ W[N,K]^T  (f32 accum)
// MODE: 0=store f32, 2=atomicAdd f32, 3=split bf16 (n<256 -> C3, else C2).
// ---------------------------------------------------------------------------
template <int MODE>
__global__ __launch_bounds__(256) void mfma_gemm(
    const bf16* __restrict__ A, const bf16* __restrict__ W,
    float* __restrict__ C, bf16* __restrict__ C2, bf16* __restrict__ C3,
    int M, int N, int K, int lda, int kper)
{
    __shared__ ushort Asm[128][40];
    __shared__ ushort Wsm[128][40];
    int bm = blockIdx.y * 128, bn = blockIdx.x * 128;
    int tid = threadIdx.x;
    int w = tid >> 6, l = tid & 63;
    int wr = w >> 1, wc = w & 1;
    int kb = (l >> 4) * 8, lr = l & 15;

    f32x4 acc[4][4];
    #pragma unroll
    for (int i = 0; i < 4; i++)
        #pragma unroll
        for (int j = 0; j < 4; j++) acc[i][j] = (f32x4){0.f, 0.f, 0.f, 0.f};

    int kbeg = blockIdx.z * kper;
    for (int k0 = kbeg; k0 < kbeg + kper; k0 += 32) {
        #pragma unroll
        for (int i = 0; i < 2; i++) {
            int idx = tid + 256 * i;
            int row = idx >> 2, kq = (idx & 3) * 8;
            *(float4*)&Asm[row][kq] =
                *(const float4*)&A[(size_t)(bm + row) * lda + k0 + kq];
            float4 wv = make_float4(0.f, 0.f, 0.f, 0.f);
            if (bn + row < N)
                wv = *(const float4*)&W[(size_t)(bn + row) * K + k0 + kq];
            *(float4*)&Wsm[row][kq] = wv;
        }
        __syncthreads();
        bf16x8 af[4], bfr[4];
        #pragma unroll
        for (int f = 0; f < 4; f++) {
            af[f]  = *(const bf16x8*)&Asm[wr * 64 + f * 16 + lr][kb];
            bfr[f] = *(const bf16x8*)&Wsm[wc * 64 + f * 16 + lr][kb];
        }
        #pragma unroll
        for (int mf = 0; mf < 4; mf++)
            #pragma unroll
            for (int nf = 0; nf < 4; nf++)
                acc[mf][nf] = __builtin_amdgcn_mfma_f32_16x16x32_bf16(
                    af[mf], bfr[nf], acc[mf][nf], 0, 0, 0);
        __syncthreads();
    }

    int rbase = bm + wr * 64 + (l >> 4) * 4;
    int cbase = bn + wc * 64 + lr;
    #pragma unroll
    for (int mf = 0; mf < 4; mf++) {
        #pragma unroll
        for (int nf = 0; nf < 4; nf++) {
            int n = cbase + nf * 16;
            if (n >= N) continue;
            #pragma unroll
            for (int r = 0; r < 4; r++) {
                int m = rbase + mf * 16 + r;
                float v = acc[mf][nf][r];
                if (MODE == 0) C[(size_t)m * N + n] = v;
                else if (MODE == 2) atomicAdd(&C[(size_t)m * N + n], v);
                else {
                    if (n < 256) C3[(size_t)m * 256 + n] = __float2bfloat16(v);
                    else C2[(size_t)m * 256 + (n - 256)] = __float2bfloat16(v);
                }
            }
        }
    }
}

__device__ __forceinline__ float softplus_f(float x) {
    return (x > 8.f) ? x : __logf(1.f + __expf(x));
}

// ---------------------------------------------------------------------------
// K4: fused conv+SiLU, x_proj MFMA, AND scan phase-1 (all same (b,ch) block).
// Phase A: u -> LDS + global. Phase B: xdbl = u @ xw^T -> LDS + global.
// Phase C: scan1 recurrence from LDS; writes qbuf[b][ch][n][d] + sbuf.
// ---------------------------------------------------------------------------
__global__ __launch_bounds__(256) void k_convx1(
    const bf16* __restrict__ xs, const float* __restrict__ cw,
    const float* __restrict__ cb, const bf16* __restrict__ xw,
    const float* __restrict__ dtw, const float* __restrict__ dtb_,
    const float* __restrict__ a1s, const int* __restrict__ pwf,
    const float* __restrict__ A_log,
    bf16* __restrict__ ubf, float* __restrict__ xdbl,
    float* __restrict__ q, float* __restrict__ sdt_out)
{
    int blk = blockIdx.x;              // b*NCH + ch
    int b = blk >> 6, ch = blk & (NCH - 1);
    int d = threadIdx.x;
    __shared__ ushort u_lds[16][264];
    __shared__ float xdbl_lds[16][40];

    // ---- phase A: depthwise conv + silu, channel d, 16 tokens ----
    float c0 = cw[d * 4], c1 = cw[d * 4 + 1], c2 = cw[d * 4 + 2], c3 = cw[d * 4 + 3];
    float cbias = cb[d];
    int tloc0 = ch * CHL;
    const bf16* col = xs + ((size_t)b * TOK + tloc0) * 256 + d;
    float xv[19];
    #pragma unroll
    for (int i = 0; i < 19; i++) {
        int tg = tloc0 - 3 + i;
        xv[i] = (tg >= 0) ? __bfloat162float(col[(size_t)(i - 3) * 256]) : 0.f;
    }
    bf16* uout = ubf + ((size_t)b * TOK + tloc0) * 256 + d;
    #pragma unroll
    for (int t = 0; t < 16; t++) {
        float a = cbias + xv[t] * c0 + xv[t + 1] * c1 + xv[t + 2] * c2 + xv[t + 3] * c3;
        float s = __fdividef(a, 1.f + __expf(-a));
        bf16 ub = __float2bfloat16(s);
        u_lds[t][d] = *(ushort*)&ub;
        uout[(size_t)t * 256] = ub;
    }
    __syncthreads();

    // ---- phase B: xdbl = u @ xw^T  (M=16, N=40, K=256), 3 waves ----
    int w = d >> 6, l = d & 63;
    if (w < 3) {
        int lr = l & 15, kb = (l >> 4) * 8;
        int nrow = w * 16 + lr;
        bool valid = nrow < 40;
        const bf16* wrow = xw + (size_t)nrow * 256;
        f32x4 acc = (f32x4){0.f, 0.f, 0.f, 0.f};
        #pragma unroll
        for (int ks = 0; ks < 8; ks++) {
            bf16x8 af = *(const bf16x8*)&u_lds[lr][ks * 32 + kb];
            bf16x8 bfr = (bf16x8){0, 0, 0, 0, 0, 0, 0, 0};
            if (valid) bfr = *(const bf16x8*)&wrow[ks * 32 + kb];
            acc = __builtin_amdgcn_mfma_f32_16x16x32_bf16(af, bfr, acc, 0, 0, 0);
        }
        int ncol = w * 16 + (l & 15);
        if (ncol < 40) {
            #pragma unroll
            for (int r = 0; r < 4; r++) {
                int t = (l >> 4) * 4 + r;
                xdbl_lds[t][ncol] = acc[r];
                xdbl[((size_t)b * TOK + tloc0 + t) * 40 + ncol] = acc[r];
            }
        }
    }
    __syncthreads();

    // ---- phase C: scan1 recurrence (h0=0) from LDS ----
    float a1 = a1s[d];
    bool pw = pwf[d] != 0;
    float w8[8];
    #pragma unroll
    for (int j = 0; j < 8; j++) w8[j] = dtw[d * 8 + j];
    float bias = dtb_[d];
    float h[16];
    #pragma unroll
    for (int n = 0; n < 16; n++) h[n] = 0.f;
    float sdt = 0.f;

    if (pw) {
        for (int t = 0; t < CHL; t++) {
            float acc = bias;
            #pragma unroll
            for (int j = 0; j < 8; j++) acc += xdbl_lds[t][j] * w8[j];
            float dtv = softplus_f(acc);
            ushort uraw = u_lds[t][d];
            float uu = __bfloat162float(*(bf16*)&uraw);
            sdt += dtv;
            float du = dtv * uu;
            float dA[16];
            dA[0] = __expf(dtv * a1);
            #pragma unroll
            for (int n = 1; n < 16; n++) dA[n] = dA[(n - 1) >> 1] * dA[n >> 1];
            #pragma unroll
            for (int n = 0; n < 16; n++)
                h[n] = dA[n] * h[n] + du * xdbl_lds[t][8 + n];
        }
    } else {
        float Av[16];
        #pragma unroll
        for (int n = 0; n < 16; n++) Av[n] = -__expf(A_log[d * 16 + n]);
        for (int t = 0; t < CHL; t++) {
            float acc = bias;
            #pragma unroll
            for (int j = 0; j < 8; j++) acc += xdbl_lds[t][j] * w8[j];
            float dtv = softplus_f(acc);
            ushort uraw = u_lds[t][d];
            float uu = __bfloat162float(*(bf16*)&uraw);
            sdt += dtv;
            float du = dtv * uu;
            #pragma unroll
            for (int n = 0; n < 16; n++)
                h[n] = __expf(dtv * Av[n]) * h[n] + du * xdbl_lds[t][8 + n];
        }
    }
    float* qp = q + ((size_t)blk * 16) * 256 + d;
    #pragma unroll
    for (int n = 0; n < 16; n++) qp[(size_t)n * 256] = h[n];
    sdt_out[(size_t)blk * 256 + d] = sdt;
}

// scan2: cross-chunk combine; thread = (b,n,d), d fastest -> coalesced.
__global__ __launch_bounds__(256) void k_scan2(
    const float* __restrict__ A_log, const float* __restrict__ sdt_in,
    float* __restrict__ q)
{
    int idx = blockIdx.x * 256 + threadIdx.x;   // 65536
    int d = idx & 255, n = (idx >> 8) & 15, b = idx >> 12;
    float Av = -__expf(A_log[d * 16 + n]);
    float h = 0.f;
    for (int g = 0; g < NCH / 8; g++) {
        float qv[8], sv[8];
        #pragma unroll
        for (int j = 0; j < 8; j++) {
            size_t blk = (size_t)b * NCH + g * 8 + j;
            qv[j] = q[(blk * 16 + n) * 256 + d];
            sv[j] = sdt_in[blk * 256 + d];
        }
        #pragma unroll
        for (int j = 0; j < 8; j++) {
            size_t blk = (size_t)b * NCH + g * 8 + j;
            float P = __expf(Av * sv[j]);
            q[(blk * 16 + n) * 256 + d] = h;
            h = P * h + qv[j];
        }
    }
}

// ---------------------------------------------------------------------------
// K6: scan phase-3 + fused out_proj + residual add (non-atomic: block owns
// its 16 tokens). y -> LDS bf16, then 4 waves: x[16x128] += y @ ow^T.
// ---------------------------------------------------------------------------
__global__ __launch_bounds__(256) void k_scan3o(
    const bf16* __restrict__ ubf, const float* __restrict__ xdbl,
    const float* __restrict__ dtw, const float* __restrict__ dtb_,
    const float* __restrict__ a1s, const int* __restrict__ pwf,
    const float* __restrict__ A_log, const float* __restrict__ Dp,
    const float* __restrict__ q, const bf16* __restrict__ zbf,
    const bf16* __restrict__ ow, float* __restrict__ x)
{
    int blk = blockIdx.x;
    int b = blk >> 6, ch = blk & (NCH - 1);
    int d = threadIdx.x;
    __shared__ ushort y_lds[16][264];

    float a1 = a1s[d];
    bool pw = pwf[d] != 0;
    float w8[8];
    #pragma unroll
    for (int j = 0; j < 8; j++) w8[j] = dtw[d * 8 + j];
    float bias = dtb_[d];
    float Dv = Dp[d];
    float h[16];
    const float* qp = q + ((size_t)blk * 16) * 256 + d;
    #pragma unroll
    for (int n = 0; n < 16; n++) h[n] = qp[(size_t)n * 256];

    size_t tok0 = (size_t)b * TOK + ch * CHL;
    const float* row = xdbl + tok0 * 40;
    const bf16* up = ubf + tok0 * 256 + d;
    const bf16* zp = zbf + tok0 * 256 + d;

    if (pw) {
        for (int t = 0; t < CHL; t++, row += 40, up += 256, zp += 256) {
            float acc = bias;
            #pragma unroll
            for (int j = 0; j < 8; j++) acc += row[j] * w8[j];
            float dtv = softplus_f(acc);
            float uu = __bfloat162float(*up);
            float du = dtv * uu;
            float dA[16];
            dA[0] = __expf(dtv * a1);
            #pragma unroll
            for (int n = 1; n < 16; n++) dA[n] = dA[(n - 1) >> 1] * dA[n >> 1];
            float ya = 0.f;
            #pragma unroll
            for (int n = 0; n < 16; n++) {
                h[n] = dA[n] * h[n] + du * row[8 + n];
                ya += h[n] * row[24 + n];
            }
            float zv = __bfloat162float(*zp);
            float sz = __fdividef(zv, 1.f + __expf(-zv));
            bf16 yb = __float2bfloat16((ya + uu * Dv) * sz);
            y_lds[t][d] = *(ushort*)&yb;
        }
    } else {
        float Av[16];
        #pragma unroll
        for (int n = 0; n < 16; n++) Av[n] = -__expf(A_log[d * 16 + n]);
        for (int t = 0; t < CHL; t++, row += 40, up += 256, zp += 256) {
            float acc = bias;
            #pragma unroll
            for (int j = 0; j < 8; j++) acc += row[j] * w8[j];
            float dtv = softplus_f(acc);
            float uu = __bfloat162float(*up);
            float du = dtv * uu;
            float ya = 0.f;
            #pragma unroll
            for (int n = 0; n < 16; n++) {
                h[n] = __expf(dtv * Av[n]) * h[n] + du * row[8 + n];
                ya += h[n] * row[24 + n];
            }
            float zv = __bfloat162float(*zp);
            float sz = __fdividef(zv, 1.f + __expf(-zv));
            bf16 yb = __float2bfloat16((ya + uu * Dv) * sz);
            y_lds[t][d] = *(ushort*)&yb;
        }
    }
    __syncthreads();

    // out_proj: wave w covers output cols w*32 .. w*32+31 (two 16-col tiles)
    int w = d >> 6, l = d & 63;
    int lr = l & 15, kb = (l >> 4) * 8;
    const bf16* wr0 = ow + (size_t)(w * 32 + lr) * 256;
    const bf16* wr1 = ow + (size_t)(w * 32 + 16 + lr) * 256;
    f32x4 acc0 = (f32x4){0.f, 0.f, 0.f, 0.f};
    f32x4 acc1 = (f32x4){0.f, 0.f, 0.f, 0.f};
    #pragma unroll
    for (int ks = 0; ks < 8; ks++) {
        bf16x8 af = *(const bf16x8*)&y_lds[lr][ks * 32 + kb];
        bf16x8 b0 = *(const bf16x8*)&wr0[ks * 32 + kb];
        bf16x8 b1 = *(const bf16x8*)&wr1[ks * 32 + kb];
        acc0 = __builtin_amdgcn_mfma_f32_16x16x32_bf16(af, b0, acc0, 0, 0, 0);
        acc1 = __builtin_amdgcn_mfma_f32_16x16x32_bf16(af, b1, acc1, 0, 0, 0);
    }
    // C/D: col = lane&15 (within n-tile), row = (lane>>4)*4 + r (token)
    int trow = (l >> 4) * 4;
    float* xp = x + (tok0 + trow) * (size_t)DMODEL;
    #pragma unroll
    for (int r = 0; r < 4; r++) {
        xp[(size_t)r * DMODEL + w * 32 + lr]      += acc0[r];
        xp[(size_t)r * DMODEL + w * 32 + 16 + lr] += acc1[r];
    }
}

// ---------------------------------------------------------------------------
// K7: head epilogue
// ---------------------------------------------------------------------------
__global__ __launch_bounds__(256) void k_head_ep(
    const float* __restrict__ hg, const float* __restrict__ hb,
    const float* __restrict__ means, const float* __restrict__ stdev,
    float* __restrict__ out)
{
    int i = blockIdx.x * 256 + threadIdx.x;
    if (i >= BATCH * PRED * NVARS) return;
    int c = i & 31;
    int p = (i >> 5) % PRED;
    int b = i / (PRED * NVARS);
    float v = hg[((size_t)b * NVARS + c) * PRED + p] + hb[p];
    out[i] = v * stdev[b * NVARS + c] + means[b * NVARS + c];
}

// ---------------------------------------------------------------------------
extern "C" void kernel_launch(void* const* d_in, const int* in_sizes, int n_in,
                              void* d_out, int out_size, void* d_ws, size_t ws_size,
                              hipStream_t stream)
{
    const float* x_enc   = (const float*)d_in[0];
    const float* patch_w = (const float*)d_in[4];
    const float* norm_w  = (const float*)d_in[5];
    const float* in_w    = (const float*)d_in[6];
    const float* conv_w  = (const float*)d_in[7];
    const float* conv_b  = (const float*)d_in[8];
    const float* xp_w    = (const float*)d_in[9];
    const float* dt_w    = (const float*)d_in[10];
    const float* dt_b    = (const float*)d_in[11];
    const float* A_log   = (const float*)d_in[12];
    const float* D_skip  = (const float*)d_in[13];
    const float* out_w   = (const float*)d_in[14];
    const float* fnorm_w = (const float*)d_in[15];
    const float* head_w  = (const float*)d_in[16];
    const float* head_b  = (const float*)d_in[17];
    float* out = (float*)d_out;

    float* ws    = (float*)d_ws;
    float* means = ws;                          // 512
    float* stdv  = ws + 512;                    // 512
    float* x     = ws + 1024;                   // NTOK*128 f32   8MB
    float* xdbl  = x    + (size_t)NTOK * 128;   // NTOK*40      2.6MB
    float* qbuf  = xdbl + (size_t)NTOK * 40;    // 16*64*16*256  16.8MB
    float* sbuf  = qbuf + (size_t)BATCH * NCH * DIN * DSTATE;  // 1MB
    float* hg    = sbuf + (size_t)BATCH * NCH * DIN;           // 512*96
    float* a1s   = hg + 512 * PRED;             // NLAYER*DIN
    int*   pwf   = (int*)(a1s + NLAYER * DIN);  // NLAYER*DIN
    bf16* hbf  = (bf16*)(pwf + NLAYER * DIN);   // NTOK*128   4MB
    bf16* xsbf = hbf + (size_t)NTOK * 128;      // NTOK*256   8MB
    bf16* zbf  = xsbf + (size_t)NTOK * 256;     // NTOK*256   8MB
    bf16* ubf  = zbf + (size_t)NTOK * 256;      // NTOK*256   8MB
    bf16* wbf  = ubf + (size_t)NTOK * 256;      // 610304     1.2MB

    const int NIW = NLAYER * 2 * DIN * DMODEL;         // 131072
    const int NXW = NLAYER * (DTRANK + 2*DSTATE) * DIN;// 20480
    const int NOW = NLAYER * DMODEL * DIN;             // 65536
    const int NHW = PRED * LTOK * DMODEL;              // 393216
    bf16* iwbf = wbf;
    bf16* xwbf = iwbf + NIW;
    bf16* owbf = xwbf + NXW;
    bf16* hwbf = owbf + NOW;

    int castN = NIW + NXW + NOW + NHW + NLAYER * DIN + 512 * PRED;
    k_cast<<<(castN + 255) / 256, 256, 0, stream>>>(
        in_w, xp_w, out_w, head_w, NIW, NXW, NOW, NHW, wbf, A_log, a1s, pwf, hg);

    k_instnorm_patch<<<BATCH * NVARS, 256, 0, stream>>>(x_enc, patch_w, x, means, stdv);

    for (int layer = 0; layer < NLAYER; layer++) {
        const float* nw  = norm_w + layer * DMODEL;
        const float* cw  = conv_w + layer * DIN * DCONV;
        const float* cb  = conv_b + layer * DIN;
        const float* dw  = dt_w   + layer * DIN * DTRANK;
        const float* db  = dt_b   + layer * DIN;
        const float* al  = A_log  + layer * DIN * DSTATE;
        const float* dp  = D_skip + layer * DIN;
        const float* a1l = a1s + layer * DIN;
        const int*   pwl = pwf + layer * DIN;
        const bf16* iw = iwbf + (size_t)layer * 2 * DIN * DMODEL;
        const bf16* xw = xwbf + (size_t)layer * (DTRANK + 2 * DSTATE) * DIN;
        const bf16* ow = owbf + (size_t)layer * DMODEL * DIN;

        k_rmsnorm<<<NTOK / 4, 256, 0, stream>>>(x, nw, hbf);
        // xz = h @ in_w^T, split: cols 0..255 -> xsbf, 256..511 -> zbf
        mfma_gemm<3><<<dim3(4, NTOK / 128, 1), 256, 0, stream>>>(
            hbf, iw, nullptr, zbf, xsbf, NTOK, 512, DMODEL, DMODEL, DMODEL);
        // fused conv + x_proj + scan1
        k_convx1<<<BATCH * NCH, 256, 0, stream>>>(
            xsbf, cw, cb, xw, dw, db, a1l, pwl, al, ubf, xdbl, qbuf, sbuf);
        k_scan2<<<(BATCH * DIN * DSTATE) / 256, 256, 0, stream>>>(al, sbuf, qbuf);
        // fused scan3 + out_proj + residual
        k_scan3o<<<BATCH * NCH, 256, 0, stream>>>(
            ubf, xdbl, dw, db, a1l, pwl, al, dp, qbuf, zbf, ow, x);
    }

    // final norm -> hbf; head = split-K MFMA into hg (zeroed by k_cast)
    k_rmsnorm<<<NTOK / 4, 256, 0, stream>>>(x, fnorm_w, hbf);
    mfma_gemm<2><<<dim3(1, 4, 32), 256, 0, stream>>>(
        hbf, hwbf, hg, nullptr, nullptr, 512, PRED, LTOK * DMODEL, LTOK * DMODEL, 128);
    k_head_ep<<<(BATCH * PRED * NVARS + 255) / 256, 256, 0, stream>>>(
        hg, head_b, means, stdv, out);
}

// Round 10
// 156.379 us; speedup vs baseline: 1.9056x; 1.1017x over previous
//
#include <hip/hip_runtime.h>
#include <hip/hip_bf16.h>
#include <math.h>

#define BATCH   16
#define SEQL    512
#define NVARS   32
#define PATCHL  16
#define LTOK    32
#define DMODEL  128
#define NLAYER  2
#define DIN     256
#define DSTATE  16
#define DTRANK  8
#define DCONV   4
#define PRED    96
#define TOK     1024
#define NTOK    (BATCH*TOK)   // 16384
#define EPSF    1e-5f
#define NCH     64            // time chunks
#define CHL     16            // TOK/NCH

typedef __attribute__((ext_vector_type(8))) short bf16x8;
typedef __attribute__((ext_vector_type(4))) float f32x4;
typedef __hip_bfloat16 bf16;

// ---------------------------------------------------------------------------
// K0: cast weights to bf16 + scan consts + zero hg (one grid)
// ---------------------------------------------------------------------------
__global__ __launch_bounds__(256) void k_cast(
    const float* __restrict__ a, const float* __restrict__ b,
    const float* __restrict__ c, const float* __restrict__ d,
    int na, int nb, int nc, int nd, bf16* __restrict__ out,
    const float* __restrict__ A_log, float* __restrict__ a1s, int* __restrict__ pwf,
    float* __restrict__ hg)
{
    int i = blockIdx.x * 256 + threadIdx.x;
    int total = na + nb + nc + nd;
    if (i < total) {
        float v;
        if (i < na) v = a[i];
        else if (i < na + nb) v = b[i - na];
        else if (i < na + nb + nc) v = c[i - na - nb];
        else v = d[i - na - nb - nc];
        out[i] = __float2bfloat16(v);
    } else if (i < total + NLAYER * DIN) {
        int j = i - total;
        const float* al = A_log + (size_t)j * DSTATE;
        float a1 = -__expf(al[0]);
        bool pw = true;
        #pragma unroll
        for (int n = 1; n < 16; n++) {
            float av = -__expf(al[n]);
            pw = pw && (fabsf(av - (n + 1) * a1) <= 1e-5f * fabsf((n + 1) * a1));
        }
        a1s[j] = a1;
        pwf[j] = pw ? 1 : 0;
    } else if (i < total + NLAYER * DIN + 512 * PRED) {
        hg[i - total - NLAYER * DIN] = 0.f;
    }
}

// ---------------------------------------------------------------------------
// K1: instance norm + patch embed + FUSED layer-0 RMSNorm (block owns rows)
// ---------------------------------------------------------------------------
__global__ __launch_bounds__(256) void k_instnorm_patch(
    const float* __restrict__ x_enc, const float* __restrict__ patch_w,
    const float* __restrict__ nw0,
    float* __restrict__ x, bf16* __restrict__ hbf,
    float* __restrict__ means, float* __restrict__ stdev)
{
    int bc = blockIdx.x;
    int b = bc >> 5, c = bc & 31;
    __shared__ float xe[SEQL];
    __shared__ float pw[DMODEL * PATCHL];
    __shared__ float red[8];
    __shared__ float enc_lds[LTOK][DMODEL];
    int tid = threadIdx.x;

    float v0 = x_enc[((size_t)b * SEQL + tid) * NVARS + c];
    float v1 = x_enc[((size_t)b * SEQL + tid + 256) * NVARS + c];
    for (int i = tid; i < DMODEL * PATCHL; i += 256) pw[i] = patch_w[i];

    float s = v0 + v1;
    for (int o = 1; o < 64; o <<= 1) s += __shfl_xor(s, o, 64);
    if ((tid & 63) == 0) red[tid >> 6] = s;
    __syncthreads();
    float mean = (red[0] + red[1] + red[2] + red[3]) * (1.f / 512.f);

    float d0 = v0 - mean, d1 = v1 - mean;
    float q = d0 * d0 + d1 * d1;
    for (int o = 1; o < 64; o <<= 1) q += __shfl_xor(q, o, 64);
    if ((tid & 63) == 0) red[4 + (tid >> 6)] = q;
    __syncthreads();
    float var = (red[4] + red[5] + red[6] + red[7]) * (1.f / 512.f);
    float sd = sqrtf(var + EPSF);
    float rsd = 1.f / sd;
    if (tid == 0) { means[bc] = mean; stdev[bc] = sd; }

    xe[tid] = d0 * rsd;
    xe[tid + 256] = d1 * rsd;
    __syncthreads();

    size_t base = ((size_t)b * TOK + (size_t)c * LTOK) * DMODEL;
    for (int o = tid; o < LTOK * DMODEL; o += 256) {
        int l = o >> 7, dm = o & 127;
        float acc = 0.f;
        #pragma unroll
        for (int p = 0; p < PATCHL; p++) acc += xe[l * PATCHL + p] * pw[dm * PATCHL + p];
        x[base + o] = acc;
        enc_lds[l][dm] = acc;
    }
    __syncthreads();

    // fused RMSNorm (layer 0): token t = tid>>3 (32 tokens), g = tid&7 (16 cols each)
    int t = tid >> 3, g = tid & 7;
    float vals[16];
    float ss = 0.f;
    #pragma unroll
    for (int j = 0; j < 16; j++) { vals[j] = enc_lds[t][g * 16 + j]; ss += vals[j] * vals[j]; }
    ss += __shfl_xor(ss, 1, 64);
    ss += __shfl_xor(ss, 2, 64);
    ss += __shfl_xor(ss, 4, 64);
    float rms = rsqrtf(ss * (1.f / DMODEL) + EPSF);
    bf16* hp = hbf + (base + (size_t)t * DMODEL);
    #pragma unroll
    for (int j = 0; j < 16; j++)
        hp[g * 16 + j] = __float2bfloat16(vals[j] * rms * nw0[g * 16 + j]);
}

// ---------------------------------------------------------------------------
// K3: MFMA bf16 GEMM.  MODE: 2=atomicAdd f32, 3=split bf16 (xs/z).
// ---------------------------------------------------------------------------
template <int MODE>
__global__ __launch_bounds__(256) void mfma_gemm(
    const bf16* __restrict__ A, const bf16* __restrict__ W,
    float* __restrict__ C, bf16* __restrict__ C2, bf16* __restrict__ C3,
    int M, int N, int K, int lda, int kper)
{
    __shared__ ushort Asm[128][40];
    __shared__ ushort Wsm[128][40];
    int bm = blockIdx.y * 128, bn = blockIdx.x * 128;
    int tid = threadIdx.x;
    int w = tid >> 6, l = tid & 63;
    int wr = w >> 1, wc = w & 1;
    int kb = (l >> 4) * 8, lr = l & 15;

    f32x4 acc[4][4];
    #pragma unroll
    for (int i = 0; i < 4; i++)
        #pragma unroll
        for (int j = 0; j < 4; j++) acc[i][j] = (f32x4){0.f, 0.f, 0.f, 0.f};

    int kbeg = blockIdx.z * kper;
    for (int k0 = kbeg; k0 < kbeg + kper; k0 += 32) {
        #pragma unroll
        for (int i = 0; i < 2; i++) {
            int idx = tid + 256 * i;
            int row = idx >> 2, kq = (idx & 3) * 8;
            *(float4*)&Asm[row][kq] =
                *(const float4*)&A[(size_t)(bm + row) * lda + k0 + kq];
            float4 wv = make_float4(0.f, 0.f, 0.f, 0.f);
            if (bn + row < N)
                wv = *(const float4*)&W[(size_t)(bn + row) * K + k0 + kq];
            *(float4*)&Wsm[row][kq] = wv;
        }
        __syncthreads();
        bf16x8 af[4], bfr[4];
        #pragma unroll
        for (int f = 0; f < 4; f++) {
            af[f]  = *(const bf16x8*)&Asm[wr * 64 + f * 16 + lr][kb];
            bfr[f] = *(const bf16x8*)&Wsm[wc * 64 + f * 16 + lr][kb];
        }
        #pragma unroll
        for (int mf = 0; mf < 4; mf++)
            #pragma unroll
            for (int nf = 0; nf < 4; nf++)
                acc[mf][nf] = __builtin_amdgcn_mfma_f32_16x16x32_bf16(
                    af[mf], bfr[nf], acc[mf][nf], 0, 0, 0);
        __syncthreads();
    }

    int rbase = bm + wr * 64 + (l >> 4) * 4;
    int cbase = bn + wc * 64 + lr;
    #pragma unroll
    for (int mf = 0; mf < 4; mf++) {
        #pragma unroll
        for (int nf = 0; nf < 4; nf++) {
            int n = cbase + nf * 16;
            if (n >= N) continue;
            #pragma unroll
            for (int r = 0; r < 4; r++) {
                int m = rbase + mf * 16 + r;
                float v = acc[mf][nf][r];
                if (MODE == 2) atomicAdd(&C[(size_t)m * N + n], v);
                else {
                    if (n < 256) C3[(size_t)m * 256 + n] = __float2bfloat16(v);
                    else C2[(size_t)m * 256 + (n - 256)] = __float2bfloat16(v);
                }
            }
        }
    }
}

__device__ __forceinline__ float softplus_f(float x) {
    return (x > 8.f) ? x : __logf(1.f + __expf(x));
}

// ---------------------------------------------------------------------------
// K4: fused conv+SiLU + x_proj MFMA + scan phase-1. qbuf now bf16.
// ---------------------------------------------------------------------------
__global__ __launch_bounds__(256) void k_convx1(
    const bf16* __restrict__ xs, const float* __restrict__ cw,
    const float* __restrict__ cb, const bf16* __restrict__ xw,
    const float* __restrict__ dtw, const float* __restrict__ dtb_,
    const float* __restrict__ a1s, const int* __restrict__ pwf,
    const float* __restrict__ A_log,
    bf16* __restrict__ ubf, float* __restrict__ xdbl,
    bf16* __restrict__ q, float* __restrict__ sdt_out)
{
    int blk = blockIdx.x;              // b*NCH + ch
    int b = blk >> 6, ch = blk & (NCH - 1);
    int d = threadIdx.x;
    __shared__ ushort u_lds[16][264];
    __shared__ float xdbl_lds[16][40];

    float c0 = cw[d * 4], c1 = cw[d * 4 + 1], c2 = cw[d * 4 + 2], c3 = cw[d * 4 + 3];
    float cbias = cb[d];
    int tloc0 = ch * CHL;
    const bf16* col = xs + ((size_t)b * TOK + tloc0) * 256 + d;
    float xv[19];
    #pragma unroll
    for (int i = 0; i < 19; i++) {
        int tg = tloc0 - 3 + i;
        xv[i] = (tg >= 0) ? __bfloat162float(col[(size_t)(i - 3) * 256]) : 0.f;
    }
    bf16* uout = ubf + ((size_t)b * TOK + tloc0) * 256 + d;
    #pragma unroll
    for (int t = 0; t < 16; t++) {
        float a = cbias + xv[t] * c0 + xv[t + 1] * c1 + xv[t + 2] * c2 + xv[t + 3] * c3;
        float s = __fdividef(a, 1.f + __expf(-a));
        bf16 ub = __float2bfloat16(s);
        u_lds[t][d] = *(ushort*)&ub;
        uout[(size_t)t * 256] = ub;
    }
    __syncthreads();

    int w = d >> 6, l = d & 63;
    if (w < 3) {
        int lr = l & 15, kb = (l >> 4) * 8;
        int nrow = w * 16 + lr;
        bool valid = nrow < 40;
        const bf16* wrow = xw + (size_t)nrow * 256;
        f32x4 acc = (f32x4){0.f, 0.f, 0.f, 0.f};
        #pragma unroll
        for (int ks = 0; ks < 8; ks++) {
            bf16x8 af = *(const bf16x8*)&u_lds[lr][ks * 32 + kb];
            bf16x8 bfr = (bf16x8){0, 0, 0, 0, 0, 0, 0, 0};
            if (valid) bfr = *(const bf16x8*)&wrow[ks * 32 + kb];
            acc = __builtin_amdgcn_mfma_f32_16x16x32_bf16(af, bfr, acc, 0, 0, 0);
        }
        int ncol = w * 16 + (l & 15);
        if (ncol < 40) {
            #pragma unroll
            for (int r = 0; r < 4; r++) {
                int t = (l >> 4) * 4 + r;
                xdbl_lds[t][ncol] = acc[r];
                xdbl[((size_t)b * TOK + tloc0 + t) * 40 + ncol] = acc[r];
            }
        }
    }
    __syncthreads();

    float a1 = a1s[d];
    bool pw = pwf[d] != 0;
    float w8[8];
    #pragma unroll
    for (int j = 0; j < 8; j++) w8[j] = dtw[d * 8 + j];
    float bias = dtb_[d];
    float h[16];
    #pragma unroll
    for (int n = 0; n < 16; n++) h[n] = 0.f;
    float sdt = 0.f;

    if (pw) {
        for (int t = 0; t < CHL; t++) {
            float acc = bias;
            #pragma unroll
            for (int j = 0; j < 8; j++) acc += xdbl_lds[t][j] * w8[j];
            float dtv = softplus_f(acc);
            ushort uraw = u_lds[t][d];
            float uu = __bfloat162float(*(bf16*)&uraw);
            sdt += dtv;
            float du = dtv * uu;
            float dA[16];
            dA[0] = __expf(dtv * a1);
            #pragma unroll
            for (int n = 1; n < 16; n++) dA[n] = dA[(n - 1) >> 1] * dA[n >> 1];
            #pragma unroll
            for (int n = 0; n < 16; n++)
                h[n] = dA[n] * h[n] + du * xdbl_lds[t][8 + n];
        }
    } else {
        float Av[16];
        #pragma unroll
        for (int n = 0; n < 16; n++) Av[n] = -__expf(A_log[d * 16 + n]);
        for (int t = 0; t < CHL; t++) {
            float acc = bias;
            #pragma unroll
            for (int j = 0; j < 8; j++) acc += xdbl_lds[t][j] * w8[j];
            float dtv = softplus_f(acc);
            ushort uraw = u_lds[t][d];
            float uu = __bfloat162float(*(bf16*)&uraw);
            sdt += dtv;
            float du = dtv * uu;
            #pragma unroll
            for (int n = 0; n < 16; n++)
                h[n] = __expf(dtv * Av[n]) * h[n] + du * xdbl_lds[t][8 + n];
        }
    }
    bf16* qp = q + ((size_t)blk * 16) * 256 + d;
    #pragma unroll
    for (int n = 0; n < 16; n++) qp[(size_t)n * 256] = __float2bfloat16(h[n]);
    sdt_out[(size_t)blk * 256 + d] = sdt;
}

// scan2: cross-chunk combine on bf16 qbuf; f32 accumulation.
__global__ __launch_bounds__(256) void k_scan2(
    const float* __restrict__ A_log, const float* __restrict__ sdt_in,
    bf16* __restrict__ q)
{
    int idx = blockIdx.x * 256 + threadIdx.x;   // 65536
    int d = idx & 255, n = (idx >> 8) & 15, b = idx >> 12;
    float Av = -__expf(A_log[d * 16 + n]);
    float h = 0.f;
    for (int g = 0; g < NCH / 8; g++) {
        float qv[8], sv[8];
        #pragma unroll
        for (int j = 0; j < 8; j++) {
            size_t blk = (size_t)b * NCH + g * 8 + j;
            qv[j] = __bfloat162float(q[(blk * 16 + n) * 256 + d]);
            sv[j] = sdt_in[blk * 256 + d];
        }
        #pragma unroll
        for (int j = 0; j < 8; j++) {
            size_t blk = (size_t)b * NCH + g * 8 + j;
            float P = __expf(Av * sv[j]);
            q[(blk * 16 + n) * 256 + d] = __float2bfloat16(h);
            h = P * h + qv[j];
        }
    }
}

// ---------------------------------------------------------------------------
// K6: scan phase-3 + out_proj + residual + FUSED next-RMSNorm (block owns rows)
// ---------------------------------------------------------------------------
__global__ __launch_bounds__(256) void k_scan3o(
    const bf16* __restrict__ ubf, const float* __restrict__ xdbl,
    const float* __restrict__ dtw, const float* __restrict__ dtb_,
    const float* __restrict__ a1s, const int* __restrict__ pwf,
    const float* __restrict__ A_log, const float* __restrict__ Dp,
    const bf16* __restrict__ q, const bf16* __restrict__ zbf,
    const bf16* __restrict__ ow, const float* __restrict__ nwn,
    float* __restrict__ x, bf16* __restrict__ hout)
{
    int blk = blockIdx.x;
    int b = blk >> 6, ch = blk & (NCH - 1);
    int d = threadIdx.x;
    __shared__ ushort y_lds[16][264];
    __shared__ float xn_lds[16][132];

    float a1 = a1s[d];
    bool pw = pwf[d] != 0;
    float w8[8];
    #pragma unroll
    for (int j = 0; j < 8; j++) w8[j] = dtw[d * 8 + j];
    float bias = dtb_[d];
    float Dv = Dp[d];
    float h[16];
    const bf16* qp = q + ((size_t)blk * 16) * 256 + d;
    #pragma unroll
    for (int n = 0; n < 16; n++) h[n] = __bfloat162float(qp[(size_t)n * 256]);

    size_t tok0 = (size_t)b * TOK + ch * CHL;
    const float* row = xdbl + tok0 * 40;
    const bf16* up = ubf + tok0 * 256 + d;
    const bf16* zp = zbf + tok0 * 256 + d;

    if (pw) {
        for (int t = 0; t < CHL; t++, row += 40, up += 256, zp += 256) {
            float acc = bias;
            #pragma unroll
            for (int j = 0; j < 8; j++) acc += row[j] * w8[j];
            float dtv = softplus_f(acc);
            float uu = __bfloat162float(*up);
            float du = dtv * uu;
            float dA[16];
            dA[0] = __expf(dtv * a1);
            #pragma unroll
            for (int n = 1; n < 16; n++) dA[n] = dA[(n - 1) >> 1] * dA[n >> 1];
            float ya = 0.f;
            #pragma unroll
            for (int n = 0; n < 16; n++) {
                h[n] = dA[n] * h[n] + du * row[8 + n];
                ya += h[n] * row[24 + n];
            }
            float zv = __bfloat162float(*zp);
            float sz = __fdividef(zv, 1.f + __expf(-zv));
            bf16 yb = __float2bfloat16((ya + uu * Dv) * sz);
            y_lds[t][d] = *(ushort*)&yb;
        }
    } else {
        float Av[16];
        #pragma unroll
        for (int n = 0; n < 16; n++) Av[n] = -__expf(A_log[d * 16 + n]);
        for (int t = 0; t < CHL; t++, row += 40, up += 256, zp += 256) {
            float acc = bias;
            #pragma unroll
            for (int j = 0; j < 8; j++) acc += row[j] * w8[j];
            float dtv = softplus_f(acc);
            float uu = __bfloat162float(*up);
            float du = dtv * uu;
            float ya = 0.f;
            #pragma unroll
            for (int n = 0; n < 16; n++) {
                h[n] = __expf(dtv * Av[n]) * h[n] + du * row[8 + n];
                ya += h[n] * row[24 + n];
            }
            float zv = __bfloat162float(*zp);
            float sz = __fdividef(zv, 1.f + __expf(-zv));
            bf16 yb = __float2bfloat16((ya + uu * Dv) * sz);
            y_lds[t][d] = *(ushort*)&yb;
        }
    }
    __syncthreads();

    // out_proj: wave w -> output cols w*32 .. w*32+31 (two 16-col tiles)
    int w = d >> 6, l = d & 63;
    int lr = l & 15, kb = (l >> 4) * 8;
    const bf16* wr0 = ow + (size_t)(w * 32 + lr) * 256;
    const bf16* wr1 = ow + (size_t)(w * 32 + 16 + lr) * 256;
    f32x4 acc0 = (f32x4){0.f, 0.f, 0.f, 0.f};
    f32x4 acc1 = (f32x4){0.f, 0.f, 0.f, 0.f};
    #pragma unroll
    for (int ks = 0; ks < 8; ks++) {
        bf16x8 af = *(const bf16x8*)&y_lds[lr][ks * 32 + kb];
        bf16x8 b0 = *(const bf16x8*)&wr0[ks * 32 + kb];
        bf16x8 b1 = *(const bf16x8*)&wr1[ks * 32 + kb];
        acc0 = __builtin_amdgcn_mfma_f32_16x16x32_bf16(af, b0, acc0, 0, 0, 0);
        acc1 = __builtin_amdgcn_mfma_f32_16x16x32_bf16(af, b1, acc1, 0, 0, 0);
    }
    int trow = (l >> 4) * 4;
    float* xp = x + (tok0 + trow) * (size_t)DMODEL;
    #pragma unroll
    for (int r = 0; r < 4; r++) {
        float v0 = xp[(size_t)r * DMODEL + w * 32 + lr] + acc0[r];
        float v1 = xp[(size_t)r * DMODEL + w * 32 + 16 + lr] + acc1[r];
        xp[(size_t)r * DMODEL + w * 32 + lr] = v0;
        xp[(size_t)r * DMODEL + w * 32 + 16 + lr] = v1;
        xn_lds[trow + r][w * 32 + lr] = v0;
        xn_lds[trow + r][w * 32 + 16 + lr] = v1;
    }
    __syncthreads();

    // fused RMSNorm for the NEXT consumer (norm_w[l+1] or final_norm_w)
    int t = d >> 4, g = d & 15;
    float vals[8];
    float ss = 0.f;
    #pragma unroll
    for (int j = 0; j < 8; j++) { vals[j] = xn_lds[t][g * 8 + j]; ss += vals[j] * vals[j]; }
    ss += __shfl_xor(ss, 1, 64);
    ss += __shfl_xor(ss, 2, 64);
    ss += __shfl_xor(ss, 4, 64);
    ss += __shfl_xor(ss, 8, 64);
    float rms = rsqrtf(ss * (1.f / DMODEL) + EPSF);
    bf16* hp = hout + (tok0 + t) * (size_t)DMODEL;
    #pragma unroll
    for (int j = 0; j < 8; j++)
        hp[g * 8 + j] = __float2bfloat16(vals[j] * rms * nwn[g * 8 + j]);
}

// ---------------------------------------------------------------------------
// K7: head epilogue
// ---------------------------------------------------------------------------
__global__ __launch_bounds__(256) void k_head_ep(
    const float* __restrict__ hg, const float* __restrict__ hb,
    const float* __restrict__ means, const float* __restrict__ stdev,
    float* __restrict__ out)
{
    int i = blockIdx.x * 256 + threadIdx.x;
    if (i >= BATCH * PRED * NVARS) return;
    int c = i & 31;
    int p = (i >> 5) % PRED;
    int b = i / (PRED * NVARS);
    float v = hg[((size_t)b * NVARS + c) * PRED + p] + hb[p];
    out[i] = v * stdev[b * NVARS + c] + means[b * NVARS + c];
}

// ---------------------------------------------------------------------------
extern "C" void kernel_launch(void* const* d_in, const int* in_sizes, int n_in,
                              void* d_out, int out_size, void* d_ws, size_t ws_size,
                              hipStream_t stream)
{
    const float* x_enc   = (const float*)d_in[0];
    const float* patch_w = (const float*)d_in[4];
    const float* norm_w  = (const float*)d_in[5];
    const float* in_w    = (const float*)d_in[6];
    const float* conv_w  = (const float*)d_in[7];
    const float* conv_b  = (const float*)d_in[8];
    const float* xp_w    = (const float*)d_in[9];
    const float* dt_w    = (const float*)d_in[10];
    const float* dt_b    = (const float*)d_in[11];
    const float* A_log   = (const float*)d_in[12];
    const float* D_skip  = (const float*)d_in[13];
    const float* out_w   = (const float*)d_in[14];
    const float* fnorm_w = (const float*)d_in[15];
    const float* head_w  = (const float*)d_in[16];
    const float* head_b  = (const float*)d_in[17];
    float* out = (float*)d_out;

    float* ws    = (float*)d_ws;
    float* means = ws;                          // 512
    float* stdv  = ws + 512;                    // 512
    float* x     = ws + 1024;                   // NTOK*128 f32   8MB
    float* xdbl  = x    + (size_t)NTOK * 128;   // NTOK*40      2.6MB
    float* sbuf  = xdbl + (size_t)NTOK * 40;    // 16*64*256     1MB
    float* hg    = sbuf + (size_t)BATCH * NCH * DIN;   // 512*96
    float* a1s   = hg + 512 * PRED;             // NLAYER*DIN
    int*   pwf   = (int*)(a1s + NLAYER * DIN);  // NLAYER*DIN
    bf16* hbf  = (bf16*)(pwf + NLAYER * DIN);   // NTOK*128   4MB
    bf16* xsbf = hbf + (size_t)NTOK * 128;      // NTOK*256   8MB
    bf16* zbf  = xsbf + (size_t)NTOK * 256;     // NTOK*256   8MB
    bf16* ubf  = zbf + (size_t)NTOK * 256;      // NTOK*256   8MB
    bf16* qbuf = ubf + (size_t)NTOK * 256;      // 16*64*16*256 8.4MB
    bf16* wbf  = qbuf + (size_t)BATCH * NCH * DSTATE * DIN;  // 1.2MB

    const int NIW = NLAYER * 2 * DIN * DMODEL;         // 131072
    const int NXW = NLAYER * (DTRANK + 2*DSTATE) * DIN;// 20480
    const int NOW = NLAYER * DMODEL * DIN;             // 65536
    const int NHW = PRED * LTOK * DMODEL;              // 393216
    bf16* iwbf = wbf;
    bf16* xwbf = iwbf + NIW;
    bf16* owbf = xwbf + NXW;
    bf16* hwbf = owbf + NOW;

    int castN = NIW + NXW + NOW + NHW + NLAYER * DIN + 512 * PRED;
    k_cast<<<(castN + 255) / 256, 256, 0, stream>>>(
        in_w, xp_w, out_w, head_w, NIW, NXW, NOW, NHW, wbf, A_log, a1s, pwf, hg);

    // instnorm + patch + layer-0 rmsnorm -> x, hbf
    k_instnorm_patch<<<BATCH * NVARS, 256, 0, stream>>>(
        x_enc, patch_w, norm_w, x, hbf, means, stdv);

    for (int layer = 0; layer < NLAYER; layer++) {
        const float* cw  = conv_w + layer * DIN * DCONV;
        const float* cb  = conv_b + layer * DIN;
        const float* dw  = dt_w   + layer * DIN * DTRANK;
        const float* db  = dt_b   + layer * DIN;
        const float* al  = A_log  + layer * DIN * DSTATE;
        const float* dp  = D_skip + layer * DIN;
        const float* a1l = a1s + layer * DIN;
        const int*   pwl = pwf + layer * DIN;
        const bf16* iw = iwbf + (size_t)layer * 2 * DIN * DMODEL;
        const bf16* xw = xwbf + (size_t)layer * (DTRANK + 2 * DSTATE) * DIN;
        const bf16* ow = owbf + (size_t)layer * DMODEL * DIN;
        // next norm: layer0 -> norm_w[1], layer1 -> final_norm_w
        const float* nwn = (layer + 1 < NLAYER) ? (norm_w + (layer + 1) * DMODEL) : fnorm_w;

        // xz = h @ in_w^T, split: cols 0..255 -> xsbf, 256..511 -> zbf
        mfma_gemm<3><<<dim3(4, NTOK / 128, 1), 256, 0, stream>>>(
            hbf, iw, nullptr, zbf, xsbf, NTOK, 512, DMODEL, DMODEL, DMODEL);
        // fused conv + x_proj + scan1
        k_convx1<<<BATCH * NCH, 256, 0, stream>>>(
            xsbf, cw, cb, xw, dw, db, a1l, pwl, al, ubf, xdbl, qbuf, sbuf);
        k_scan2<<<(BATCH * DIN * DSTATE) / 256, 256, 0, stream>>>(al, sbuf, qbuf);
        // fused scan3 + out_proj + residual + next rmsnorm
        k_scan3o<<<BATCH * NCH, 256, 0, stream>>>(
            ubf, xdbl, dw, db, a1l, pwl, al, dp, qbuf, zbf, ow, nwn, x, hbf);
    }

    // head = split-K MFMA into hg (zeroed by k_cast), then epilogue
    mfma_gemm<2><<<dim3(1, 4, 32), 256, 0, stream>>>(
        hbf, hwbf, hg, nullptr, nullptr, 512, PRED, LTOK * DMODEL, LTOK * DMODEL, 128);
    k_head_ep<<<(BATCH * PRED * NVARS + 255) / 256, 256, 0, stream>>>(
        hg, head_b, means, stdv, out);
}

// Round 11
// 154.955 us; speedup vs baseline: 1.9231x; 1.0092x over previous
//
#include <hip/hip_runtime.h>
#include <hip/hip_bf16.h>
#include <math.h>

#define BATCH   16
#define SEQL    512
#define NVARS   32
#define PATCHL  16
#define LTOK    32
#define DMODEL  128
#define NLAYER  2
#define DIN     256
#define DSTATE  16
#define DTRANK  8
#define DCONV   4
#define PRED    96
#define TOK     1024
#define NTOK    (BATCH*TOK)   // 16384
#define EPSF    1e-5f
#define NCH     64            // time chunks
#define CHL     16            // TOK/NCH

typedef __attribute__((ext_vector_type(8))) short bf16x8;
typedef __attribute__((ext_vector_type(4))) float f32x4;
typedef __hip_bfloat16 bf16;

// ---------------------------------------------------------------------------
// K0: cast weights to bf16 + scan consts + zero hg (one grid)
// ---------------------------------------------------------------------------
__global__ __launch_bounds__(256) void k_cast(
    const float* __restrict__ a, const float* __restrict__ b,
    const float* __restrict__ c, const float* __restrict__ d,
    int na, int nb, int nc, int nd, bf16* __restrict__ out,
    const float* __restrict__ A_log, float* __restrict__ a1s, int* __restrict__ pwf,
    float* __restrict__ hg)
{
    int i = blockIdx.x * 256 + threadIdx.x;
    int total = na + nb + nc + nd;
    if (i < total) {
        float v;
        if (i < na) v = a[i];
        else if (i < na + nb) v = b[i - na];
        else if (i < na + nb + nc) v = c[i - na - nb];
        else v = d[i - na - nb - nc];
        out[i] = __float2bfloat16(v);
    } else if (i < total + NLAYER * DIN) {
        int j = i - total;
        const float* al = A_log + (size_t)j * DSTATE;
        float a1 = -__expf(al[0]);
        bool pw = true;
        #pragma unroll
        for (int n = 1; n < 16; n++) {
            float av = -__expf(al[n]);
            pw = pw && (fabsf(av - (n + 1) * a1) <= 1e-5f * fabsf((n + 1) * a1));
        }
        a1s[j] = a1;
        pwf[j] = pw ? 1 : 0;
    } else if (i < total + NLAYER * DIN + 512 * PRED) {
        hg[i - total - NLAYER * DIN] = 0.f;
    }
}

// ---------------------------------------------------------------------------
// K1: instance norm + patch embed + FUSED layer-0 RMSNorm
// ---------------------------------------------------------------------------
__global__ __launch_bounds__(256) void k_instnorm_patch(
    const float* __restrict__ x_enc, const float* __restrict__ patch_w,
    const float* __restrict__ nw0,
    float* __restrict__ x, bf16* __restrict__ hbf,
    float* __restrict__ means, float* __restrict__ stdev)
{
    int bc = blockIdx.x;
    int b = bc >> 5, c = bc & 31;
    __shared__ float xe[SEQL];
    __shared__ float pw[DMODEL * PATCHL];
    __shared__ float red[8];
    __shared__ float enc_lds[LTOK][DMODEL];
    int tid = threadIdx.x;

    float v0 = x_enc[((size_t)b * SEQL + tid) * NVARS + c];
    float v1 = x_enc[((size_t)b * SEQL + tid + 256) * NVARS + c];
    for (int i = tid; i < DMODEL * PATCHL; i += 256) pw[i] = patch_w[i];

    float s = v0 + v1;
    for (int o = 1; o < 64; o <<= 1) s += __shfl_xor(s, o, 64);
    if ((tid & 63) == 0) red[tid >> 6] = s;
    __syncthreads();
    float mean = (red[0] + red[1] + red[2] + red[3]) * (1.f / 512.f);

    float d0 = v0 - mean, d1 = v1 - mean;
    float q = d0 * d0 + d1 * d1;
    for (int o = 1; o < 64; o <<= 1) q += __shfl_xor(q, o, 64);
    if ((tid & 63) == 0) red[4 + (tid >> 6)] = q;
    __syncthreads();
    float var = (red[4] + red[5] + red[6] + red[7]) * (1.f / 512.f);
    float sd = sqrtf(var + EPSF);
    float rsd = 1.f / sd;
    if (tid == 0) { means[bc] = mean; stdev[bc] = sd; }

    xe[tid] = d0 * rsd;
    xe[tid + 256] = d1 * rsd;
    __syncthreads();

    size_t base = ((size_t)b * TOK + (size_t)c * LTOK) * DMODEL;
    for (int o = tid; o < LTOK * DMODEL; o += 256) {
        int l = o >> 7, dm = o & 127;
        float acc = 0.f;
        #pragma unroll
        for (int p = 0; p < PATCHL; p++) acc += xe[l * PATCHL + p] * pw[dm * PATCHL + p];
        x[base + o] = acc;
        enc_lds[l][dm] = acc;
    }
    __syncthreads();

    int t = tid >> 3, g = tid & 7;
    float vals[16];
    float ss = 0.f;
    #pragma unroll
    for (int j = 0; j < 16; j++) { vals[j] = enc_lds[t][g * 16 + j]; ss += vals[j] * vals[j]; }
    ss += __shfl_xor(ss, 1, 64);
    ss += __shfl_xor(ss, 2, 64);
    ss += __shfl_xor(ss, 4, 64);
    float rms = rsqrtf(ss * (1.f / DMODEL) + EPSF);
    bf16* hp = hbf + (base + (size_t)t * DMODEL);
    #pragma unroll
    for (int j = 0; j < 16; j++)
        hp[g * 16 + j] = __float2bfloat16(vals[j] * rms * nw0[g * 16 + j]);
}

// ---------------------------------------------------------------------------
// K3: MFMA bf16 GEMM (head only): C[M,N] += A @ W^T via atomicAdd, split-K.
// ---------------------------------------------------------------------------
__global__ __launch_bounds__(256) void mfma_gemm_at(
    const bf16* __restrict__ A, const bf16* __restrict__ W,
    float* __restrict__ C, int M, int N, int K, int kper)
{
    __shared__ ushort Asm[128][40];
    __shared__ ushort Wsm[128][40];
    int bm = blockIdx.y * 128, bn = blockIdx.x * 128;
    int tid = threadIdx.x;
    int w = tid >> 6, l = tid & 63;
    int wr = w >> 1, wc = w & 1;
    int kb = (l >> 4) * 8, lr = l & 15;

    f32x4 acc[4][4];
    #pragma unroll
    for (int i = 0; i < 4; i++)
        #pragma unroll
        for (int j = 0; j < 4; j++) acc[i][j] = (f32x4){0.f, 0.f, 0.f, 0.f};

    int kbeg = blockIdx.z * kper;
    for (int k0 = kbeg; k0 < kbeg + kper; k0 += 32) {
        #pragma unroll
        for (int i = 0; i < 2; i++) {
            int idx = tid + 256 * i;
            int row = idx >> 2, kq = (idx & 3) * 8;
            *(float4*)&Asm[row][kq] =
                *(const float4*)&A[(size_t)(bm + row) * K + k0 + kq];
            float4 wv = make_float4(0.f, 0.f, 0.f, 0.f);
            if (bn + row < N)
                wv = *(const float4*)&W[(size_t)(bn + row) * K + k0 + kq];
            *(float4*)&Wsm[row][kq] = wv;
        }
        __syncthreads();
        bf16x8 af[4], bfr[4];
        #pragma unroll
        for (int f = 0; f < 4; f++) {
            af[f]  = *(const bf16x8*)&Asm[wr * 64 + f * 16 + lr][kb];
            bfr[f] = *(const bf16x8*)&Wsm[wc * 64 + f * 16 + lr][kb];
        }
        #pragma unroll
        for (int mf = 0; mf < 4; mf++)
            #pragma unroll
            for (int nf = 0; nf < 4; nf++)
                acc[mf][nf] = __builtin_amdgcn_mfma_f32_16x16x32_bf16(
                    af[mf], bfr[nf], acc[mf][nf], 0, 0, 0);
        __syncthreads();
    }

    int rbase = bm + wr * 64 + (l >> 4) * 4;
    int cbase = bn + wc * 64 + lr;
    #pragma unroll
    for (int mf = 0; mf < 4; mf++) {
        #pragma unroll
        for (int nf = 0; nf < 4; nf++) {
            int n = cbase + nf * 16;
            if (n >= N) continue;
            #pragma unroll
            for (int r = 0; r < 4; r++)
                atomicAdd(&C[(size_t)(rbase + mf * 16 + r) * N + n], acc[mf][nf][r]);
        }
    }
}

__device__ __forceinline__ float softplus_f(float x) {
    return (x > 8.f) ? x : __logf(1.f + __expf(x));
}

// ---------------------------------------------------------------------------
// K4: fused in_proj(xs half) MFMA + conv+SiLU + x_proj MFMA + scan phase-1.
// Block = (b,ch). Stages hbf rows tok0-16..tok0+15 (halo), computes
// xs = hbf @ iwA^T in-block (zero rows reproduce causal padding).
// ---------------------------------------------------------------------------
__global__ __launch_bounds__(256) void k_convx1(
    const bf16* __restrict__ hbf, const bf16* __restrict__ iwA,
    const float* __restrict__ cw, const float* __restrict__ cb,
    const bf16* __restrict__ xw,
    const float* __restrict__ dtw, const float* __restrict__ dtb_,
    const float* __restrict__ a1s, const int* __restrict__ pwf,
    const float* __restrict__ A_log,
    bf16* __restrict__ ubf, float* __restrict__ xdbl,
    bf16* __restrict__ q, float* __restrict__ sdt_out)
{
    int blk = blockIdx.x;              // b*NCH + ch
    int b = blk >> 6, ch = blk & (NCH - 1);
    int d = threadIdx.x;
    __shared__ ushort hb_lds[32][136];   // hbf rows tok0-16..tok0+15
    __shared__ ushort xs_lds[32][264];   // xs (bf16) for same rows
    __shared__ ushort u_lds[16][264];
    __shared__ float xdbl_lds[16][40];

    int tloc0 = ch * CHL;

    // ---- stage hbf tile (zero for tl<0) ----
    {
        int r = d >> 3, c8 = (d & 7) * 16;
        int tl = tloc0 - 16 + r;
        float4 v0 = make_float4(0.f, 0.f, 0.f, 0.f), v1 = v0;
        if (tl >= 0) {
            const bf16* src = hbf + ((size_t)b * TOK + tl) * DMODEL + c8;
            v0 = *(const float4*)src;
            v1 = *(const float4*)(src + 8);
        }
        *(float4*)&hb_lds[r][c8] = v0;
        *(float4*)&hb_lds[r][c8 + 8] = v1;
    }
    __syncthreads();

    // ---- xs = hbf @ iwA^T  (M=32, N=256, K=128); 4 waves x 64 cols ----
    {
        int w = d >> 6, l = d & 63;
        int lr = l & 15, kb = (l >> 4) * 8;
        f32x4 accx[2][4];
        #pragma unroll
        for (int mf = 0; mf < 2; mf++)
            #pragma unroll
            for (int nf = 0; nf < 4; nf++) accx[mf][nf] = (f32x4){0.f, 0.f, 0.f, 0.f};
        #pragma unroll
        for (int ks = 0; ks < 4; ks++) {
            bf16x8 af0 = *(const bf16x8*)&hb_lds[lr][ks * 32 + kb];
            bf16x8 af1 = *(const bf16x8*)&hb_lds[16 + lr][ks * 32 + kb];
            #pragma unroll
            for (int nf = 0; nf < 4; nf++) {
                const bf16* wrow = iwA + (size_t)(w * 64 + nf * 16 + lr) * DMODEL;
                bf16x8 bfr = *(const bf16x8*)&wrow[ks * 32 + kb];
                accx[0][nf] = __builtin_amdgcn_mfma_f32_16x16x32_bf16(af0, bfr, accx[0][nf], 0, 0, 0);
                accx[1][nf] = __builtin_amdgcn_mfma_f32_16x16x32_bf16(af1, bfr, accx[1][nf], 0, 0, 0);
            }
        }
        #pragma unroll
        for (int mf = 0; mf < 2; mf++)
            #pragma unroll
            for (int nf = 0; nf < 4; nf++) {
                int ncol = w * 64 + nf * 16 + lr;
                #pragma unroll
                for (int r = 0; r < 4; r++) {
                    int row = mf * 16 + (l >> 4) * 4 + r;
                    bf16 xb = __float2bfloat16(accx[mf][nf][r]);
                    xs_lds[row][ncol] = *(ushort*)&xb;
                }
            }
    }
    __syncthreads();

    // ---- conv + SiLU (xs rows 13..31 = tokens tok0-3..tok0+15) ----
    float c0 = cw[d * 4], c1 = cw[d * 4 + 1], c2 = cw[d * 4 + 2], c3 = cw[d * 4 + 3];
    float cbias = cb[d];
    float xv[19];
    #pragma unroll
    for (int i = 0; i < 19; i++) {
        ushort raw = xs_lds[13 + i][d];
        xv[i] = __bfloat162float(*(bf16*)&raw);
    }
    bf16* uout = ubf + ((size_t)b * TOK + tloc0) * 256 + d;
    #pragma unroll
    for (int t = 0; t < 16; t++) {
        float a = cbias + xv[t] * c0 + xv[t + 1] * c1 + xv[t + 2] * c2 + xv[t + 3] * c3;
        float s = __fdividef(a, 1.f + __expf(-a));
        bf16 ub = __float2bfloat16(s);
        u_lds[t][d] = *(ushort*)&ub;
        uout[(size_t)t * 256] = ub;
    }
    __syncthreads();

    // ---- x_proj: xdbl = u @ xw^T  (M=16, N=40, K=256), 3 waves ----
    {
        int w = d >> 6, l = d & 63;
        if (w < 3) {
            int lr = l & 15, kb = (l >> 4) * 8;
            int nrow = w * 16 + lr;
            bool valid = nrow < 40;
            const bf16* wrow = xw + (size_t)nrow * 256;
            f32x4 acc = (f32x4){0.f, 0.f, 0.f, 0.f};
            #pragma unroll
            for (int ks = 0; ks < 8; ks++) {
                bf16x8 af = *(const bf16x8*)&u_lds[lr][ks * 32 + kb];
                bf16x8 bfr = (bf16x8){0, 0, 0, 0, 0, 0, 0, 0};
                if (valid) bfr = *(const bf16x8*)&wrow[ks * 32 + kb];
                acc = __builtin_amdgcn_mfma_f32_16x16x32_bf16(af, bfr, acc, 0, 0, 0);
            }
            int ncol = w * 16 + (l & 15);
            if (ncol < 40) {
                #pragma unroll
                for (int r = 0; r < 4; r++) {
                    int t = (l >> 4) * 4 + r;
                    xdbl_lds[t][ncol] = acc[r];
                    xdbl[((size_t)b * TOK + tloc0 + t) * 40 + ncol] = acc[r];
                }
            }
        }
    }
    __syncthreads();

    // ---- scan phase-1 (h0 = 0) ----
    float a1 = a1s[d];
    bool pw = pwf[d] != 0;
    float w8[8];
    #pragma unroll
    for (int j = 0; j < 8; j++) w8[j] = dtw[d * 8 + j];
    float bias = dtb_[d];
    float h[16];
    #pragma unroll
    for (int n = 0; n < 16; n++) h[n] = 0.f;
    float sdt = 0.f;

    if (pw) {
        for (int t = 0; t < CHL; t++) {
            float acc = bias;
            #pragma unroll
            for (int j = 0; j < 8; j++) acc += xdbl_lds[t][j] * w8[j];
            float dtv = softplus_f(acc);
            ushort uraw = u_lds[t][d];
            float uu = __bfloat162float(*(bf16*)&uraw);
            sdt += dtv;
            float du = dtv * uu;
            float dA[16];
            dA[0] = __expf(dtv * a1);
            #pragma unroll
            for (int n = 1; n < 16; n++) dA[n] = dA[(n - 1) >> 1] * dA[n >> 1];
            #pragma unroll
            for (int n = 0; n < 16; n++)
                h[n] = dA[n] * h[n] + du * xdbl_lds[t][8 + n];
        }
    } else {
        float Av[16];
        #pragma unroll
        for (int n = 0; n < 16; n++) Av[n] = -__expf(A_log[d * 16 + n]);
        for (int t = 0; t < CHL; t++) {
            float acc = bias;
            #pragma unroll
            for (int j = 0; j < 8; j++) acc += xdbl_lds[t][j] * w8[j];
            float dtv = softplus_f(acc);
            ushort uraw = u_lds[t][d];
            float uu = __bfloat162float(*(bf16*)&uraw);
            sdt += dtv;
            float du = dtv * uu;
            #pragma unroll
            for (int n = 0; n < 16; n++)
                h[n] = __expf(dtv * Av[n]) * h[n] + du * xdbl_lds[t][8 + n];
        }
    }
    bf16* qp = q + ((size_t)blk * 16) * 256 + d;
    #pragma unroll
    for (int n = 0; n < 16; n++) qp[(size_t)n * 256] = __float2bfloat16(h[n]);
    sdt_out[(size_t)blk * 256 + d] = sdt;
}

// scan2: cross-chunk combine on bf16 qbuf; f32 accumulation.
__global__ __launch_bounds__(256) void k_scan2(
    const float* __restrict__ A_log, const float* __restrict__ sdt_in,
    bf16* __restrict__ q)
{
    int idx = blockIdx.x * 256 + threadIdx.x;   // 65536
    int d = idx & 255, n = (idx >> 8) & 15, b = idx >> 12;
    float Av = -__expf(A_log[d * 16 + n]);
    float h = 0.f;
    for (int g = 0; g < NCH / 8; g++) {
        float qv[8], sv[8];
        #pragma unroll
        for (int j = 0; j < 8; j++) {
            size_t blk = (size_t)b * NCH + g * 8 + j;
            qv[j] = __bfloat162float(q[(blk * 16 + n) * 256 + d]);
            sv[j] = sdt_in[blk * 256 + d];
        }
        #pragma unroll
        for (int j = 0; j < 8; j++) {
            size_t blk = (size_t)b * NCH + g * 8 + j;
            float P = __expf(Av * sv[j]);
            q[(blk * 16 + n) * 256 + d] = __float2bfloat16(h);
            h = P * h + qv[j];
        }
    }
}

// ---------------------------------------------------------------------------
// K6: fused in_proj(z half) MFMA + scan phase-3 + out_proj + residual +
// next-RMSNorm. z computed in-block from own hbf rows (read before overwrite).
// ---------------------------------------------------------------------------
__global__ __launch_bounds__(256) void k_scan3o(
    const bf16* __restrict__ ubf, const float* __restrict__ xdbl,
    const bf16* __restrict__ iwZ,
    const float* __restrict__ dtw, const float* __restrict__ dtb_,
    const float* __restrict__ a1s, const int* __restrict__ pwf,
    const float* __restrict__ A_log, const float* __restrict__ Dp,
    const bf16* __restrict__ q, const bf16* __restrict__ ow,
    const float* __restrict__ nwn,
    float* __restrict__ x, bf16* __restrict__ hbf)
{
    int blk = blockIdx.x;
    int b = blk >> 6, ch = blk & (NCH - 1);
    int d = threadIdx.x;
    __shared__ ushort hz_lds[16][136];
    __shared__ ushort z_lds[16][264];
    __shared__ ushort y_lds[16][264];
    __shared__ float xn_lds[16][132];

    size_t tok0 = (size_t)b * TOK + ch * CHL;

    // ---- stage own hbf rows ----
    {
        int r = d >> 4, c8 = (d & 15) * 8;
        *(float4*)&hz_lds[r][c8] = *(const float4*)(hbf + (tok0 + r) * DMODEL + c8);
    }
    __syncthreads();

    // ---- z = hbf @ iwZ^T  (M=16, N=256, K=128), 4 waves x 64 cols ----
    {
        int w = d >> 6, l = d & 63;
        int lr = l & 15, kb = (l >> 4) * 8;
        f32x4 accz[4];
        #pragma unroll
        for (int nf = 0; nf < 4; nf++) accz[nf] = (f32x4){0.f, 0.f, 0.f, 0.f};
        #pragma unroll
        for (int ks = 0; ks < 4; ks++) {
            bf16x8 af = *(const bf16x8*)&hz_lds[lr][ks * 32 + kb];
            #pragma unroll
            for (int nf = 0; nf < 4; nf++) {
                const bf16* wrow = iwZ + (size_t)(w * 64 + nf * 16 + lr) * DMODEL;
                bf16x8 bfr = *(const bf16x8*)&wrow[ks * 32 + kb];
                accz[nf] = __builtin_amdgcn_mfma_f32_16x16x32_bf16(af, bfr, accz[nf], 0, 0, 0);
            }
        }
        #pragma unroll
        for (int nf = 0; nf < 4; nf++) {
            int ncol = w * 64 + nf * 16 + lr;
            #pragma unroll
            for (int r = 0; r < 4; r++) {
                bf16 zb = __float2bfloat16(accz[nf][r]);
                z_lds[(l >> 4) * 4 + r][ncol] = *(ushort*)&zb;
            }
        }
    }
    __syncthreads();

    // ---- scan phase-3 ----
    float a1 = a1s[d];
    bool pw = pwf[d] != 0;
    float w8[8];
    #pragma unroll
    for (int j = 0; j < 8; j++) w8[j] = dtw[d * 8 + j];
    float bias = dtb_[d];
    float Dv = Dp[d];
    float h[16];
    const bf16* qp = q + ((size_t)blk * 16) * 256 + d;
    #pragma unroll
    for (int n = 0; n < 16; n++) h[n] = __bfloat162float(qp[(size_t)n * 256]);

    const float* row = xdbl + tok0 * 40;
    const bf16* up = ubf + tok0 * 256 + d;

    if (pw) {
        for (int t = 0; t < CHL; t++, row += 40, up += 256) {
            float acc = bias;
            #pragma unroll
            for (int j = 0; j < 8; j++) acc += row[j] * w8[j];
            float dtv = softplus_f(acc);
            float uu = __bfloat162float(*up);
            float du = dtv * uu;
            float dA[16];
            dA[0] = __expf(dtv * a1);
            #pragma unroll
            for (int n = 1; n < 16; n++) dA[n] = dA[(n - 1) >> 1] * dA[n >> 1];
            float ya = 0.f;
            #pragma unroll
            for (int n = 0; n < 16; n++) {
                h[n] = dA[n] * h[n] + du * row[8 + n];
                ya += h[n] * row[24 + n];
            }
            ushort zraw = z_lds[t][d];
            float zv = __bfloat162float(*(bf16*)&zraw);
            float sz = __fdividef(zv, 1.f + __expf(-zv));
            bf16 yb = __float2bfloat16((ya + uu * Dv) * sz);
            y_lds[t][d] = *(ushort*)&yb;
        }
    } else {
        float Av[16];
        #pragma unroll
        for (int n = 0; n < 16; n++) Av[n] = -__expf(A_log[d * 16 + n]);
        for (int t = 0; t < CHL; t++, row += 40, up += 256) {
            float acc = bias;
            #pragma unroll
            for (int j = 0; j < 8; j++) acc += row[j] * w8[j];
            float dtv = softplus_f(acc);
            float uu = __bfloat162float(*up);
            float du = dtv * uu;
            float ya = 0.f;
            #pragma unroll
            for (int n = 0; n < 16; n++) {
                h[n] = __expf(dtv * Av[n]) * h[n] + du * row[8 + n];
                ya += h[n] * row[24 + n];
            }
            ushort zraw = z_lds[t][d];
            float zv = __bfloat162float(*(bf16*)&zraw);
            float sz = __fdividef(zv, 1.f + __expf(-zv));
            bf16 yb = __float2bfloat16((ya + uu * Dv) * sz);
            y_lds[t][d] = *(ushort*)&yb;
        }
    }
    __syncthreads();

    // ---- out_proj + residual ----
    int w = d >> 6, l = d & 63;
    int lr = l & 15, kb = (l >> 4) * 8;
    const bf16* wr0 = ow + (size_t)(w * 32 + lr) * 256;
    const bf16* wr1 = ow + (size_t)(w * 32 + 16 + lr) * 256;
    f32x4 acc0 = (f32x4){0.f, 0.f, 0.f, 0.f};
    f32x4 acc1 = (f32x4){0.f, 0.f, 0.f, 0.f};
    #pragma unroll
    for (int ks = 0; ks < 8; ks++) {
        bf16x8 af = *(const bf16x8*)&y_lds[lr][ks * 32 + kb];
        bf16x8 b0 = *(const bf16x8*)&wr0[ks * 32 + kb];
        bf16x8 b1 = *(const bf16x8*)&wr1[ks * 32 + kb];
        acc0 = __builtin_amdgcn_mfma_f32_16x16x32_bf16(af, b0, acc0, 0, 0, 0);
        acc1 = __builtin_amdgcn_mfma_f32_16x16x32_bf16(af, b1, acc1, 0, 0, 0);
    }
    int trow = (l >> 4) * 4;
    float* xp = x + (tok0 + trow) * (size_t)DMODEL;
    #pragma unroll
    for (int r = 0; r < 4; r++) {
        float v0 = xp[(size_t)r * DMODEL + w * 32 + lr] + acc0[r];
        float v1 = xp[(size_t)r * DMODEL + w * 32 + 16 + lr] + acc1[r];
        xp[(size_t)r * DMODEL + w * 32 + lr] = v0;
        xp[(size_t)r * DMODEL + w * 32 + 16 + lr] = v1;
        xn_lds[trow + r][w * 32 + lr] = v0;
        xn_lds[trow + r][w * 32 + 16 + lr] = v1;
    }
    __syncthreads();

    // ---- fused RMSNorm for next consumer ----
    int t = d >> 4, g = d & 15;
    float vals[8];
    float ss = 0.f;
    #pragma unroll
    for (int j = 0; j < 8; j++) { vals[j] = xn_lds[t][g * 8 + j]; ss += vals[j] * vals[j]; }
    ss += __shfl_xor(ss, 1, 64);
    ss += __shfl_xor(ss, 2, 64);
    ss += __shfl_xor(ss, 4, 64);
    ss += __shfl_xor(ss, 8, 64);
    float rms = rsqrtf(ss * (1.f / DMODEL) + EPSF);
    bf16* hp = hbf + (tok0 + t) * (size_t)DMODEL;
    #pragma unroll
    for (int j = 0; j < 8; j++)
        hp[g * 8 + j] = __float2bfloat16(vals[j] * rms * nwn[g * 8 + j]);
}

// ---------------------------------------------------------------------------
// K7: head epilogue
// ---------------------------------------------------------------------------
__global__ __launch_bounds__(256) void k_head_ep(
    const float* __restrict__ hg, const float* __restrict__ hb,
    const float* __restrict__ means, const float* __restrict__ stdev,
    float* __restrict__ out)
{
    int i = blockIdx.x * 256 + threadIdx.x;
    if (i >= BATCH * PRED * NVARS) return;
    int c = i & 31;
    int p = (i >> 5) % PRED;
    int b = i / (PRED * NVARS);
    float v = hg[((size_t)b * NVARS + c) * PRED + p] + hb[p];
    out[i] = v * stdev[b * NVARS + c] + means[b * NVARS + c];
}

// ---------------------------------------------------------------------------
extern "C" void kernel_launch(void* const* d_in, const int* in_sizes, int n_in,
                              void* d_out, int out_size, void* d_ws, size_t ws_size,
                              hipStream_t stream)
{
    const float* x_enc   = (const float*)d_in[0];
    const float* patch_w = (const float*)d_in[4];
    const float* norm_w  = (const float*)d_in[5];
    const float* in_w    = (const float*)d_in[6];
    const float* conv_w  = (const float*)d_in[7];
    const float* conv_b  = (const float*)d_in[8];
    const float* xp_w    = (const float*)d_in[9];
    const float* dt_w    = (const float*)d_in[10];
    const float* dt_b    = (const float*)d_in[11];
    const float* A_log   = (const float*)d_in[12];
    const float* D_skip  = (const float*)d_in[13];
    const float* out_w   = (const float*)d_in[14];
    const float* fnorm_w = (const float*)d_in[15];
    const float* head_w  = (const float*)d_in[16];
    const float* head_b  = (const float*)d_in[17];
    float* out = (float*)d_out;

    float* ws    = (float*)d_ws;
    float* means = ws;                          // 512
    float* stdv  = ws + 512;                    // 512
    float* x     = ws + 1024;                   // NTOK*128 f32   8MB
    float* xdbl  = x    + (size_t)NTOK * 128;   // NTOK*40      2.6MB
    float* sbuf  = xdbl + (size_t)NTOK * 40;    // 16*64*256     1MB
    float* hg    = sbuf + (size_t)BATCH * NCH * DIN;   // 512*96
    float* a1s   = hg + 512 * PRED;             // NLAYER*DIN
    int*   pwf   = (int*)(a1s + NLAYER * DIN);  // NLAYER*DIN
    bf16* hbf  = (bf16*)(pwf + NLAYER * DIN);   // NTOK*128   4MB
    bf16* ubf  = hbf + (size_t)NTOK * 128;      // NTOK*256   8MB
    bf16* qbuf = ubf + (size_t)NTOK * 256;      // 16*64*16*256 8.4MB
    bf16* wbf  = qbuf + (size_t)BATCH * NCH * DSTATE * DIN;  // 1.2MB

    const int NIW = NLAYER * 2 * DIN * DMODEL;         // 131072
    const int NXW = NLAYER * (DTRANK + 2*DSTATE) * DIN;// 20480
    const int NOW = NLAYER * DMODEL * DIN;             // 65536
    const int NHW = PRED * LTOK * DMODEL;              // 393216
    bf16* iwbf = wbf;
    bf16* xwbf = iwbf + NIW;
    bf16* owbf = xwbf + NXW;
    bf16* hwbf = owbf + NOW;

    int castN = NIW + NXW + NOW + NHW + NLAYER * DIN + 512 * PRED;
    k_cast<<<(castN + 255) / 256, 256, 0, stream>>>(
        in_w, xp_w, out_w, head_w, NIW, NXW, NOW, NHW, wbf, A_log, a1s, pwf, hg);

    k_instnorm_patch<<<BATCH * NVARS, 256, 0, stream>>>(
        x_enc, patch_w, norm_w, x, hbf, means, stdv);

    for (int layer = 0; layer < NLAYER; layer++) {
        const float* cw  = conv_w + layer * DIN * DCONV;
        const float* cb  = conv_b + layer * DIN;
        const float* dw  = dt_w   + layer * DIN * DTRANK;
        const float* db  = dt_b   + layer * DIN;
        const float* al  = A_log  + layer * DIN * DSTATE;
        const float* dp  = D_skip + layer * DIN;
        const float* a1l = a1s + layer * DIN;
        const int*   pwl = pwf + layer * DIN;
        const bf16* iwA = iwbf + (size_t)layer * 2 * DIN * DMODEL;          // rows 0..255
        const bf16* iwZ = iwA + (size_t)DIN * DMODEL;                       // rows 256..511
        const bf16* xw = xwbf + (size_t)layer * (DTRANK + 2 * DSTATE) * DIN;
        const bf16* ow = owbf + (size_t)layer * DMODEL * DIN;
        const float* nwn = (layer + 1 < NLAYER) ? (norm_w + (layer + 1) * DMODEL) : fnorm_w;

        // fused in_proj(xs) + conv + x_proj + scan1
        k_convx1<<<BATCH * NCH, 256, 0, stream>>>(
            hbf, iwA, cw, cb, xw, dw, db, a1l, pwl, al, ubf, xdbl, qbuf, sbuf);
        k_scan2<<<(BATCH * DIN * DSTATE) / 256, 256, 0, stream>>>(al, sbuf, qbuf);
        // fused in_proj(z) + scan3 + out_proj + residual + next rmsnorm
        k_scan3o<<<BATCH * NCH, 256, 0, stream>>>(
            ubf, xdbl, iwZ, dw, db, a1l, pwl, al, dp, qbuf, ow, nwn, x, hbf);
    }

    // head = split-K MFMA into hg (zeroed by k_cast), then epilogue
    mfma_gemm_at<<<dim3(1, 4, 32), 256, 0, stream>>>(
        hbf, hwbf, hg, 512, PRED, LTOK * DMODEL, 128);
    k_head_ep<<<(BATCH * PRED * NVARS + 255) / 256, 256, 0, stream>>>(
        hg, head_b, means, stdv, out);
}